// Round 3
// baseline (684.621 us; speedup 1.0000x reference)
//
#include <hip/hip_runtime.h>
#include <hip/hip_bf16.h>

// Sizes (runtime): N_R = 100000, N_RP1 = 200000, NNZ = 1600000, C = 128
//
// Pipeline:
//   1. memset rp1/rp2 (row counts) to 0
//   2. hist: rp[r]++ per edge (both lists)
//   3. 3-kernel scan -> rp = row_ptr; cur = copy; bincur/binstart = rp at bin bounds
//   4. partition: bin edges by row>>12 into tmp (bin-contiguous, packed 8B)
//   5. fill2: tmp -> CSR ep via atomic cursors (writes confined to ~1MB region)
//   6. prep_w: Wt[n][k] = bf16(W[k][n])
//   7. gemm_mfma: h = bf16(X @ W) via mfma_f32_16x16x32_bf16, LDS-free
//   8. spmm_out: per-row bf16 gather from h1/h2, ELU both, add, write f32 out

#define CDIM 128
#define BIN_SHIFT 12           // 4096 rows per bin
#define MAX_BINS 64            // supports n_r <= 262144
#define PCHUNK 4096            // edges per partition/fill block

typedef __attribute__((ext_vector_type(8))) short bf16x8;
typedef __attribute__((ext_vector_type(4))) float f32x4;

static __device__ __forceinline__ short f2bf(float f) {
  __hip_bfloat16 h = __float2bfloat16(f);
  union { __hip_bfloat16 h; short s; } u;
  u.h = h;
  return u.s;
}

// ---------------------------------------------------------------- histogram
__global__ __launch_bounds__(256) void hist_kernel(
    const int* __restrict__ r1, const int* __restrict__ r2,
    int* __restrict__ cnt1, int* __restrict__ cnt2, int nnz) {
  int i = blockIdx.x * 256 + threadIdx.x;
  if (i < nnz) {
    atomicAdd(&cnt1[r1[i]], 1);
    atomicAdd(&cnt2[r2[i]], 1);
  }
}

// ---------------------------------------------------------------- scan (3 passes)
__global__ __launch_bounds__(256) void scan_pass1(
    int* __restrict__ rp1, int* __restrict__ rp2, int* __restrict__ blks, int n) {
  int* rp = blockIdx.y ? rp2 : rp1;
  int t = threadIdx.x, lane = t & 63, w = t >> 6;
  int base = blockIdx.x * 2048 + t * 8;
  int a[8], sinc[8];
  int run = 0;
#pragma unroll
  for (int e = 0; e < 8; ++e) {
    int idx = base + e;
    a[e] = (idx < n) ? rp[idx] : 0;
    run += a[e];
    sinc[e] = run;
  }
  int tot = run;
  int sc = tot;
#pragma unroll
  for (int d = 1; d < 64; d <<= 1) {
    int v = __shfl_up(sc, d);
    if (lane >= d) sc += v;
  }
  __shared__ int wsum[4];
  if (lane == 63) wsum[w] = sc;
  __syncthreads();
  int woff = 0;
  for (int i = 0; i < w; ++i) woff += wsum[i];
  int texcl = woff + sc - tot;
#pragma unroll
  for (int e = 0; e < 8; ++e) {
    int idx = base + e;
    if (idx < n) rp[idx] = texcl + sinc[e] - a[e];
  }
  if (t == 255) blks[blockIdx.y * 64 + blockIdx.x] = woff + sc;
}

__global__ __launch_bounds__(64) void scan_pass2(int* __restrict__ blks, int nblk) {
  int* b = blks + blockIdx.y * 64;
  int lane = threadIdx.x;
  int v = (lane < nblk) ? b[lane] : 0;
  int sc = v;
#pragma unroll
  for (int d = 1; d < 64; d <<= 1) {
    int u = __shfl_up(sc, d);
    if (lane >= d) sc += u;
  }
  if (lane < nblk) b[lane] = sc - v;
}

__global__ __launch_bounds__(256) void scan_pass3(
    int* __restrict__ rp1, int* __restrict__ rp2,
    int* __restrict__ cur1, int* __restrict__ cur2,
    int* __restrict__ bincur, int* __restrict__ binstart,
    const int* __restrict__ blks, int n, int nnz, int nbins) {
  int* rp = blockIdx.y ? rp2 : rp1;
  int* cur = blockIdx.y ? cur2 : cur1;
  int off = blks[blockIdx.y * 64 + blockIdx.x];
  int base = blockIdx.x * 2048 + threadIdx.x * 8;
#pragma unroll
  for (int e = 0; e < 8; ++e) {
    int idx = base + e;
    if (idx < n) {
      int v = rp[idx] + off;
      rp[idx] = v;
      cur[idx] = v;
      if ((idx & ((1 << BIN_SHIFT) - 1)) == 0) {
        int b = idx >> BIN_SHIFT;
        bincur[blockIdx.y * MAX_BINS + b] = v;
        binstart[blockIdx.y * (MAX_BINS + 1) + b] = v;
      }
    }
  }
  if (blockIdx.x == 0 && blockIdx.y == 0 && threadIdx.x == 0) {
    rp1[n] = nnz;
    rp2[n] = nnz;
    binstart[nbins] = nnz;
    binstart[(MAX_BINS + 1) + nbins] = nnz;
  }
}

// ---------------------------------------------------------------- partition
// Bin edges by row>>BIN_SHIFT into tmp, bin-contiguous (bin region = CSR
// slot range [rp[bin<<12], rp[(bin+1)<<12]) since bins are row-contiguous).
// Packed entry: x = (row_in_bin << 18) | col  (12 + 18 bits), y = val bits.
__global__ __launch_bounds__(256) void partition_kernel(
    const int* __restrict__ r1, const int* __restrict__ c1, const float* __restrict__ v1,
    const int* __restrict__ r2, const int* __restrict__ c2, const float* __restrict__ v2,
    int* __restrict__ bincur, int2* __restrict__ tmp1, int2* __restrict__ tmp2, int nnz) {
  const int* r = blockIdx.y ? r2 : r1;
  const int* c = blockIdx.y ? c2 : c1;
  const float* v = blockIdx.y ? v2 : v1;
  int2* tmp = blockIdx.y ? tmp2 : tmp1;
  int* bcur = bincur + blockIdx.y * MAX_BINS;

  __shared__ int cnt[MAX_BINS], base[MAX_BINS], loff[MAX_BINS];
  int t = threadIdx.x;
  if (t < MAX_BINS) cnt[t] = 0;
  __syncthreads();

  int e0 = blockIdx.x * PCHUNK + t;
  int rows[16];
  int cols[16];
  float vals[16];
#pragma unroll
  for (int i = 0; i < 16; ++i) {
    int e = e0 + i * 256;
    rows[i] = -1;
    if (e < nnz) {
      rows[i] = r[e];
      cols[i] = c[e];
      vals[i] = v[e];
      atomicAdd(&cnt[rows[i] >> BIN_SHIFT], 1);
    }
  }
  __syncthreads();
  if (t < MAX_BINS) {
    int n = cnt[t];
    base[t] = n ? atomicAdd(&bcur[t], n) : 0;
    loff[t] = 0;
  }
  __syncthreads();
#pragma unroll
  for (int i = 0; i < 16; ++i) {
    if (rows[i] >= 0) {
      int b = rows[i] >> BIN_SHIFT;
      int o = atomicAdd(&loff[b], 1);
      int pos = base[b] + o;
      tmp[pos] = make_int2(((rows[i] & ((1 << BIN_SHIFT) - 1)) << 18) | cols[i],
                           __float_as_int(vals[i]));
    }
  }
}

// ---------------------------------------------------------------- fill (binned)
__global__ __launch_bounds__(256) void fill2_kernel(
    const int2* __restrict__ tmp1, const int2* __restrict__ tmp2,
    const int* __restrict__ binstart,
    int* __restrict__ cur1, int* __restrict__ cur2,
    int2* __restrict__ ep1, int2* __restrict__ ep2, int nnz, int nbins) {
  const int2* tmp = blockIdx.y ? tmp2 : tmp1;
  int* cur = blockIdx.y ? cur2 : cur1;
  int2* ep = blockIdx.y ? ep2 : ep1;
  __shared__ int bs[MAX_BINS + 1];
  int t = threadIdx.x;
  if (t <= nbins) bs[t] = binstart[blockIdx.y * (MAX_BINS + 1) + t];
  __syncthreads();
  int p0 = blockIdx.x * PCHUNK + t;
#pragma unroll 4
  for (int i = 0; i < 16; ++i) {
    int p = p0 + i * 256;
    if (p < nnz) {
      int2 ev = tmp[p];
      int lo = 0, hi = nbins;  // bs[nbins] = nnz > p
      while (hi - lo > 1) {
        int mid = (lo + hi) >> 1;
        if (bs[mid] <= p) lo = mid; else hi = mid;
      }
      int row = (lo << BIN_SHIFT) + ((unsigned)ev.x >> 18);
      int col = ev.x & 0x3FFFF;
      int slot = atomicAdd(&cur[row], 1);
      ep[slot] = make_int2(col, ev.y);
    }
  }
}

// ---------------------------------------------------------------- W transpose+cvt
__global__ __launch_bounds__(256) void prep_w(
    const float* __restrict__ W1, const float* __restrict__ W2,
    __hip_bfloat16* __restrict__ Wt1, __hip_bfloat16* __restrict__ Wt2) {
  const float* W = blockIdx.x ? W2 : W1;
  __hip_bfloat16* Wt = blockIdx.x ? Wt2 : Wt1;
  for (int idx = threadIdx.x; idx < CDIM * CDIM; idx += 256) {
    int k = idx >> 7, n = idx & 127;
    union { __hip_bfloat16 h; short s; } u;
    u.s = f2bf(W[idx]);
    Wt[n * CDIM + k] = u.h;
  }
}

// ---------------------------------------------------------------- MFMA GEMM
// H[row][col] = bf16( X[row][:] @ W[:][col] ),  Wt is bf16 [col][k].
__global__ __launch_bounds__(256) void gemm_mfma(
    const float* __restrict__ X, const __hip_bfloat16* __restrict__ Wt,
    __hip_bfloat16* __restrict__ H, int n_rows) {
  int t = threadIdx.x;
  int lane = t & 63, wave = t >> 6;
  int rbase = blockIdx.x * 128 + wave * 32;
  int lrow = lane & 15;
  int kq = (lane >> 4) * 8;

  int r0 = rbase + lrow;
  int r1 = r0 + 16;
  bool in0 = r0 < n_rows;
  bool in1 = r1 < n_rows;

  f32x4 acc0[8], acc1[8];
#pragma unroll
  for (int j = 0; j < 8; ++j) {
    acc0[j] = (f32x4){0.f, 0.f, 0.f, 0.f};
    acc1[j] = (f32x4){0.f, 0.f, 0.f, 0.f};
  }

  const float* x0p = X + (size_t)r0 * CDIM + kq;
  const float* x1p = X + (size_t)r1 * CDIM + kq;

  for (int kk = 0; kk < CDIM; kk += 32) {
    bf16x8 a0 = (bf16x8)(short)0, a1 = (bf16x8)(short)0;
    if (in0) {
      float4 u = *(const float4*)(x0p + kk);
      float4 v = *(const float4*)(x0p + kk + 4);
      a0[0] = f2bf(u.x); a0[1] = f2bf(u.y); a0[2] = f2bf(u.z); a0[3] = f2bf(u.w);
      a0[4] = f2bf(v.x); a0[5] = f2bf(v.y); a0[6] = f2bf(v.z); a0[7] = f2bf(v.w);
    }
    if (in1) {
      float4 u = *(const float4*)(x1p + kk);
      float4 v = *(const float4*)(x1p + kk + 4);
      a1[0] = f2bf(u.x); a1[1] = f2bf(u.y); a1[2] = f2bf(u.z); a1[3] = f2bf(u.w);
      a1[4] = f2bf(v.x); a1[5] = f2bf(v.y); a1[6] = f2bf(v.z); a1[7] = f2bf(v.w);
    }
    int k = kk + kq;
#pragma unroll
    for (int j = 0; j < 8; ++j) {
      int col = j * 16 + lrow;
      bf16x8 b = *(const bf16x8*)(Wt + (size_t)col * CDIM + k);
      acc0[j] = __builtin_amdgcn_mfma_f32_16x16x32_bf16(a0, b, acc0[j], 0, 0, 0);
      acc1[j] = __builtin_amdgcn_mfma_f32_16x16x32_bf16(a1, b, acc1[j], 0, 0, 0);
    }
  }

  int crow = rbase + (lane >> 4) * 4;
#pragma unroll
  for (int j = 0; j < 8; ++j) {
    int col = j * 16 + lrow;
#pragma unroll
    for (int r = 0; r < 4; ++r) {
      int row0 = crow + r;
      if (row0 < n_rows) {
        union { __hip_bfloat16 h; short s; } u;
        u.s = f2bf(acc0[j][r]);
        H[(size_t)row0 * CDIM + col] = u.h;
      }
      int row1 = crow + 16 + r;
      if (row1 < n_rows) {
        union { __hip_bfloat16 h; short s; } u;
        u.s = f2bf(acc1[j][r]);
        H[(size_t)row1 * CDIM + col] = u.h;
      }
    }
  }
}

// ---------------------------------------------------------------- fused SpMM + ELU + add
// one wave per output row; lane handles channels [2*lane, 2*lane+1] (bf16 pair = 4B)
// edge loop unrolled x4 for MLP (4 independent gathers in flight)
__global__ __launch_bounds__(256) void spmm_out_kernel(
    const int* __restrict__ rp1, const int2* __restrict__ ep1,
    const unsigned int* __restrict__ h1,
    const int* __restrict__ rp2, const int2* __restrict__ ep2,
    const unsigned int* __restrict__ h2,
    float* __restrict__ out, int n_r) {
  int wave = threadIdx.x >> 6;
  int lane = threadIdx.x & 63;
  int row = blockIdx.x * 4 + wave;
  if (row >= n_r) return;

  float ex[2], ey[2];
#pragma unroll
  for (int L = 0; L < 2; ++L) {
    const int* rp = L ? rp2 : rp1;
    const int2* ep = L ? ep2 : ep1;
    const unsigned int* h = L ? h2 : h1;
    float2 A0 = make_float2(0.f, 0.f), A1 = make_float2(0.f, 0.f);
    float2 A2 = make_float2(0.f, 0.f), A3 = make_float2(0.f, 0.f);
    int s = rp[row], e = rp[row + 1];
    int i = s;
    for (; i + 4 <= e; i += 4) {
      int2 e0 = ep[i], e1 = ep[i + 1], e2 = ep[i + 2], e3 = ep[i + 3];
      unsigned int p0 = h[(size_t)e0.x * 64 + lane];
      unsigned int p1 = h[(size_t)e1.x * 64 + lane];
      unsigned int p2 = h[(size_t)e2.x * 64 + lane];
      unsigned int p3 = h[(size_t)e3.x * 64 + lane];
      float v0 = __int_as_float(e0.y), v1 = __int_as_float(e1.y);
      float v2 = __int_as_float(e2.y), v3 = __int_as_float(e3.y);
      A0.x += v0 * __uint_as_float(p0 << 16);
      A0.y += v0 * __uint_as_float(p0 & 0xffff0000u);
      A1.x += v1 * __uint_as_float(p1 << 16);
      A1.y += v1 * __uint_as_float(p1 & 0xffff0000u);
      A2.x += v2 * __uint_as_float(p2 << 16);
      A2.y += v2 * __uint_as_float(p2 & 0xffff0000u);
      A3.x += v3 * __uint_as_float(p3 << 16);
      A3.y += v3 * __uint_as_float(p3 & 0xffff0000u);
    }
    for (; i < e; ++i) {
      int2 ev = ep[i];
      unsigned int p = h[(size_t)ev.x * 64 + lane];
      float v = __int_as_float(ev.y);
      A0.x += v * __uint_as_float(p << 16);
      A0.y += v * __uint_as_float(p & 0xffff0000u);
    }
    float sx = (A0.x + A1.x) + (A2.x + A3.x);
    float sy = (A0.y + A1.y) + (A2.y + A3.y);
    ex[L] = sx > 0.f ? sx : expm1f(sx);
    ey[L] = sy > 0.f ? sy : expm1f(sy);
  }

  float2 o = make_float2(ex[0] + ex[1], ey[0] + ey[1]);
  *(float2*)(out + (size_t)row * CDIM + 2 * lane) = o;
}

// ---------------------------------------------------------------- launch
extern "C" void kernel_launch(void* const* d_in, const int* in_sizes, int n_in,
                              void* d_out, int out_size, void* d_ws, size_t ws_size,
                              hipStream_t stream) {
  const float* x1  = (const float*)d_in[0];
  const float* x2  = (const float*)d_in[1];
  const float* W1  = (const float*)d_in[2];
  const float* W2  = (const float*)d_in[3];
  const float* v11 = (const float*)d_in[4];
  const float* v21 = (const float*)d_in[5];
  const int* r11   = (const int*)d_in[6];
  const int* c11   = (const int*)d_in[7];
  const int* r21   = (const int*)d_in[8];
  const int* c21   = (const int*)d_in[9];

  int n_r   = in_sizes[0] / CDIM;
  int n_rp1 = in_sizes[1] / CDIM;
  int nnz   = in_sizes[4];
  float* out = (float*)d_out;
  int nbins = (n_r + (1 << BIN_SHIFT) - 1) >> BIN_SHIFT;  // 25; must be <= MAX_BINS

  char* ws = (char*)d_ws;
  size_t off = 0;
  auto alloc = [&](size_t bytes) -> void* {
    void* p = ws + off;
    off = (off + bytes + 255) & ~(size_t)255;
    return p;
  };
  __hip_bfloat16* h1 = (__hip_bfloat16*)alloc((size_t)n_r * CDIM * 2);    // 25.6 MB
  __hip_bfloat16* h2 = (__hip_bfloat16*)alloc((size_t)n_rp1 * CDIM * 2);  // 51.2 MB
  __hip_bfloat16* Wt1 = (__hip_bfloat16*)alloc(CDIM * CDIM * 2);
  __hip_bfloat16* Wt2 = (__hip_bfloat16*)alloc(CDIM * CDIM * 2);
  int* rp1  = (int*)alloc(((size_t)n_r + 1) * 4);
  int* rp2  = (int*)alloc(((size_t)n_r + 1) * 4);
  int* cur1 = (int*)alloc((size_t)n_r * 4);
  int* cur2 = (int*)alloc((size_t)n_r * 4);
  int* blks = (int*)alloc(128 * 4);
  int* bincur   = (int*)alloc(2 * MAX_BINS * 4);
  int* binstart = (int*)alloc(2 * (MAX_BINS + 1) * 4);
  int2* ep1 = (int2*)alloc((size_t)nnz * 8);            // 12.8 MB
  int2* ep2 = (int2*)alloc((size_t)nnz * 8);            // 12.8 MB
  int2* tmp1 = (int2*)alloc((size_t)nnz * 8);           // 12.8 MB
  int2* tmp2 = (int2*)alloc((size_t)nnz * 8);           // 12.8 MB
  (void)ws_size;  // ~130 MB of workspace

  hipMemsetAsync(rp1, 0, (size_t)n_r * 4, stream);
  hipMemsetAsync(rp2, 0, (size_t)n_r * 4, stream);

  int nb_e = (nnz + 255) / 256;
  hist_kernel<<<nb_e, 256, 0, stream>>>(r11, r21, rp1, rp2, nnz);

  int nblk = (n_r + 2047) / 2048;  // 49 (must be <= 64)
  scan_pass1<<<dim3(nblk, 2), 256, 0, stream>>>(rp1, rp2, blks, n_r);
  scan_pass2<<<dim3(1, 2), 64, 0, stream>>>(blks, nblk);
  scan_pass3<<<dim3(nblk, 2), 256, 0, stream>>>(rp1, rp2, cur1, cur2,
                                                bincur, binstart, blks, n_r, nnz, nbins);

  int nb_p = (nnz + PCHUNK - 1) / PCHUNK;  // 391
  partition_kernel<<<dim3(nb_p, 2), 256, 0, stream>>>(
      r11, c11, v11, r21, c21, v21, bincur, tmp1, tmp2, nnz);
  fill2_kernel<<<dim3(nb_p, 2), 256, 0, stream>>>(
      tmp1, tmp2, binstart, cur1, cur2, ep1, ep2, nnz, nbins);

  prep_w<<<2, 256, 0, stream>>>(W1, W2, Wt1, Wt2);

  gemm_mfma<<<(n_r + 127) / 128, 256, 0, stream>>>(x1, Wt1, h1, n_r);
  gemm_mfma<<<(n_rp1 + 127) / 128, 256, 0, stream>>>(x2, Wt2, h2, n_rp1);

  spmm_out_kernel<<<(n_r + 3) / 4, 256, 0, stream>>>(
      rp1, ep1, (const unsigned int*)h1,
      rp2, ep2, (const unsigned int*)h2, out, n_r);
}

// Round 4
// 349.378 us; speedup vs baseline: 1.9595x; 1.9595x over previous
//
#include <hip/hip_runtime.h>
#include <hip/hip_bf16.h>

// Sizes (runtime): N_R = 100000, N_RP1 = 200000, NNZ = 1600000, C = 128
//
// Pipeline:
//   1. memset bcnt (per-bin counts, 2x256 ints) to 0
//   2. hist_bins: per-block LDS bin histogram -> global bcnt  (bin = row>>9)
//   3. scan_bins: exclusive scan bcnt -> binstart, bincur (1 block)
//   4. partition: bin edges by row>>9 into tmp (bin-contiguous, packed 8B)
//   5. fill3: one workgroup per bin: LDS counting sort by row ->
//             ep written SEQUENTIALLY (full lines, one XCD); rp derived in LDS
//   6. prep_w: Wt[n][k] = bf16(W[k][n])
//   7. gemm_mfma: h = bf16(X @ W) via mfma_f32_16x16x32_bf16, LDS-free
//   8. spmm_out: per-row bf16 gather from h1/h2, ELU both, add, write f32 out

#define CDIM 128
#define BIN_SHIFT 9            // 512 rows per bin
#define BIN_ROWS (1 << BIN_SHIFT)
#define MAX_BINS 256           // supports n_r <= 131072
#define PCHUNK 4096            // edges per hist/partition block
#define FCAP 12288             // LDS staging capacity (edges) in fill3

typedef __attribute__((ext_vector_type(8))) short bf16x8;
typedef __attribute__((ext_vector_type(4))) float f32x4;

static __device__ __forceinline__ short f2bf(float f) {
  __hip_bfloat16 h = __float2bfloat16(f);
  union { __hip_bfloat16 h; short s; } u;
  u.h = h;
  return u.s;
}

// ---------------------------------------------------------------- bin histogram
__global__ __launch_bounds__(256) void hist_bins(
    const int* __restrict__ r1, const int* __restrict__ r2,
    int* __restrict__ bcnt, int nnz) {
  __shared__ int c1[MAX_BINS], c2[MAX_BINS];
  int t = threadIdx.x;
  c1[t] = 0;
  c2[t] = 0;
  __syncthreads();
  int e0 = blockIdx.x * PCHUNK + t;
#pragma unroll
  for (int i = 0; i < 16; ++i) {
    int e = e0 + i * 256;
    if (e < nnz) {
      atomicAdd(&c1[r1[e] >> BIN_SHIFT], 1);
      atomicAdd(&c2[r2[e] >> BIN_SHIFT], 1);
    }
  }
  __syncthreads();
  if (c1[t]) atomicAdd(&bcnt[t], c1[t]);
  if (c2[t]) atomicAdd(&bcnt[MAX_BINS + t], c2[t]);
}

// ---------------------------------------------------------------- bin scan (1 block)
__global__ __launch_bounds__(256) void scan_bins(
    const int* __restrict__ bcnt, int* __restrict__ binstart,
    int* __restrict__ bincur, int nbins, int nnz) {
  __shared__ int ws[4];
  int t = threadIdx.x, lane = t & 63, w = t >> 6;
  for (int L = 0; L < 2; ++L) {
    int v = (t < nbins) ? bcnt[L * MAX_BINS + t] : 0;
    int sc = v;
#pragma unroll
    for (int d = 1; d < 64; d <<= 1) {
      int u = __shfl_up(sc, d);
      if (lane >= d) sc += u;
    }
    if (lane == 63) ws[w] = sc;
    __syncthreads();
    int woff = 0;
    for (int i = 0; i < w; ++i) woff += ws[i];
    int excl = woff + sc - v;
    if (t < nbins) {
      binstart[L * (MAX_BINS + 1) + t] = excl;
      bincur[L * MAX_BINS + t] = excl;
    }
    if (t == 0) binstart[L * (MAX_BINS + 1) + nbins] = nnz;
    __syncthreads();
  }
}

// ---------------------------------------------------------------- partition
// Bin edges into tmp, bin-contiguous (bin region = CSR slot range, since bins
// are row-contiguous). Packed: x = (row_in_bin << 18) | col (9+18 bits), y = val.
__global__ __launch_bounds__(256) void partition_kernel(
    const int* __restrict__ r1, const int* __restrict__ c1, const float* __restrict__ v1,
    const int* __restrict__ r2, const int* __restrict__ c2, const float* __restrict__ v2,
    int* __restrict__ bincur, int2* __restrict__ tmp1, int2* __restrict__ tmp2, int nnz) {
  const int* r = blockIdx.y ? r2 : r1;
  const int* c = blockIdx.y ? c2 : c1;
  const float* v = blockIdx.y ? v2 : v1;
  int2* tmp = blockIdx.y ? tmp2 : tmp1;
  int* bcur = bincur + blockIdx.y * MAX_BINS;

  __shared__ int cnt[MAX_BINS], base[MAX_BINS], loff[MAX_BINS];
  int t = threadIdx.x;
  cnt[t] = 0;
  __syncthreads();

  int e0 = blockIdx.x * PCHUNK + t;
  int rows[16];
  int cols[16];
  float vals[16];
#pragma unroll
  for (int i = 0; i < 16; ++i) {
    int e = e0 + i * 256;
    rows[i] = -1;
    if (e < nnz) {
      rows[i] = r[e];
      cols[i] = c[e];
      vals[i] = v[e];
      atomicAdd(&cnt[rows[i] >> BIN_SHIFT], 1);
    }
  }
  __syncthreads();
  {
    int n = cnt[t];
    base[t] = n ? atomicAdd(&bcur[t], n) : 0;
    loff[t] = 0;
  }
  __syncthreads();
#pragma unroll
  for (int i = 0; i < 16; ++i) {
    if (rows[i] >= 0) {
      int b = rows[i] >> BIN_SHIFT;
      int o = atomicAdd(&loff[b], 1);
      tmp[base[b] + o] = make_int2(((rows[i] & (BIN_ROWS - 1)) << 18) | cols[i],
                                   __float_as_int(vals[i]));
    }
  }
}

// ---------------------------------------------------------------- fill (per-bin counting sort)
// One workgroup per (bin, list). LDS histogram -> scan -> stage sorted bin in
// LDS -> sequential global write. Also writes rp for the bin's rows.
__global__ __launch_bounds__(256) void fill3_kernel(
    const int2* __restrict__ tmp1, const int2* __restrict__ tmp2,
    const int* __restrict__ binstart,
    int2* __restrict__ ep1, int2* __restrict__ ep2,
    int* __restrict__ rp1, int* __restrict__ rp2,
    int n, int nnz, int nbins) {
  int L = blockIdx.y;
  const int2* tmp = L ? tmp2 : tmp1;
  int2* ep = L ? ep2 : ep1;
  int* rp = L ? rp2 : rp1;
  int bin = blockIdx.x;
  int bs = binstart[L * (MAX_BINS + 1) + bin];
  int be = binstart[L * (MAX_BINS + 1) + bin + 1];
  int count = be - bs;

  __shared__ int cnt[BIN_ROWS];
  __shared__ int wsum[4];
  __shared__ int2 outbuf[FCAP];
  int t = threadIdx.x, lane = t & 63, w = t >> 6;
  cnt[2 * t] = 0;
  cnt[2 * t + 1] = 0;
  __syncthreads();

  // pass 1: per-row histogram
  for (int p = bs + t; p < be; p += 256) {
    int rib = (unsigned)tmp[p].x >> 18;
    atomicAdd(&cnt[rib], 1);
  }
  __syncthreads();

  // exclusive scan of cnt[512] (pairs per thread)
  int a0 = cnt[2 * t], a1 = cnt[2 * t + 1];
  int pair = a0 + a1;
  int sc = pair;
#pragma unroll
  for (int d = 1; d < 64; d <<= 1) {
    int u = __shfl_up(sc, d);
    if (lane >= d) sc += u;
  }
  if (lane == 63) wsum[w] = sc;
  __syncthreads();
  int woff = 0;
  for (int i = 0; i < w; ++i) woff += wsum[i];
  int excl = woff + sc - pair;
  cnt[2 * t] = excl;
  cnt[2 * t + 1] = excl + a0;
  // rp for this bin's rows (coalesced, from registers)
  int row0 = (bin << BIN_SHIFT) + 2 * t;
  if (row0 < n) rp[row0] = bs + excl;
  if (row0 + 1 < n) rp[row0 + 1] = bs + excl + a0;
  if (bin == nbins - 1 && t == 0) rp[n] = nnz;
  __syncthreads();

  // pass 2: place (cnt now = cursor)
  if (count <= FCAP) {
    for (int p = bs + t; p < be; p += 256) {
      int2 ev = tmp[p];
      int rib = (unsigned)ev.x >> 18;
      int slot = atomicAdd(&cnt[rib], 1);
      outbuf[slot] = make_int2(ev.x & 0x3FFFF, ev.y);
    }
    __syncthreads();
    for (int p = t; p < count; p += 256) ep[bs + p] = outbuf[p];
  } else {
    // overflow fallback (correctness only; statistically never taken)
    for (int p = bs + t; p < be; p += 256) {
      int2 ev = tmp[p];
      int rib = (unsigned)ev.x >> 18;
      int slot = atomicAdd(&cnt[rib], 1);
      ep[bs + slot] = make_int2(ev.x & 0x3FFFF, ev.y);
    }
  }
}

// ---------------------------------------------------------------- W transpose+cvt
__global__ __launch_bounds__(256) void prep_w(
    const float* __restrict__ W1, const float* __restrict__ W2,
    __hip_bfloat16* __restrict__ Wt1, __hip_bfloat16* __restrict__ Wt2) {
  const float* W = blockIdx.x ? W2 : W1;
  __hip_bfloat16* Wt = blockIdx.x ? Wt2 : Wt1;
  for (int idx = threadIdx.x; idx < CDIM * CDIM; idx += 256) {
    int k = idx >> 7, n = idx & 127;
    union { __hip_bfloat16 h; short s; } u;
    u.s = f2bf(W[idx]);
    Wt[n * CDIM + k] = u.h;
  }
}

// ---------------------------------------------------------------- MFMA GEMM
// H[row][col] = bf16( X[row][:] @ W[:][col] ),  Wt is bf16 [col][k].
__global__ __launch_bounds__(256) void gemm_mfma(
    const float* __restrict__ X, const __hip_bfloat16* __restrict__ Wt,
    __hip_bfloat16* __restrict__ H, int n_rows) {
  int t = threadIdx.x;
  int lane = t & 63, wave = t >> 6;
  int rbase = blockIdx.x * 128 + wave * 32;
  int lrow = lane & 15;
  int kq = (lane >> 4) * 8;

  int r0 = rbase + lrow;
  int r1 = r0 + 16;
  bool in0 = r0 < n_rows;
  bool in1 = r1 < n_rows;

  f32x4 acc0[8], acc1[8];
#pragma unroll
  for (int j = 0; j < 8; ++j) {
    acc0[j] = (f32x4){0.f, 0.f, 0.f, 0.f};
    acc1[j] = (f32x4){0.f, 0.f, 0.f, 0.f};
  }

  const float* x0p = X + (size_t)r0 * CDIM + kq;
  const float* x1p = X + (size_t)r1 * CDIM + kq;

  for (int kk = 0; kk < CDIM; kk += 32) {
    bf16x8 a0 = (bf16x8)(short)0, a1 = (bf16x8)(short)0;
    if (in0) {
      float4 u = *(const float4*)(x0p + kk);
      float4 v = *(const float4*)(x0p + kk + 4);
      a0[0] = f2bf(u.x); a0[1] = f2bf(u.y); a0[2] = f2bf(u.z); a0[3] = f2bf(u.w);
      a0[4] = f2bf(v.x); a0[5] = f2bf(v.y); a0[6] = f2bf(v.z); a0[7] = f2bf(v.w);
    }
    if (in1) {
      float4 u = *(const float4*)(x1p + kk);
      float4 v = *(const float4*)(x1p + kk + 4);
      a1[0] = f2bf(u.x); a1[1] = f2bf(u.y); a1[2] = f2bf(u.z); a1[3] = f2bf(u.w);
      a1[4] = f2bf(v.x); a1[5] = f2bf(v.y); a1[6] = f2bf(v.z); a1[7] = f2bf(v.w);
    }
    int k = kk + kq;
#pragma unroll
    for (int j = 0; j < 8; ++j) {
      int col = j * 16 + lrow;
      bf16x8 b = *(const bf16x8*)(Wt + (size_t)col * CDIM + k);
      acc0[j] = __builtin_amdgcn_mfma_f32_16x16x32_bf16(a0, b, acc0[j], 0, 0, 0);
      acc1[j] = __builtin_amdgcn_mfma_f32_16x16x32_bf16(a1, b, acc1[j], 0, 0, 0);
    }
  }

  int crow = rbase + (lane >> 4) * 4;
#pragma unroll
  for (int j = 0; j < 8; ++j) {
    int col = j * 16 + lrow;
#pragma unroll
    for (int r = 0; r < 4; ++r) {
      int row0 = crow + r;
      if (row0 < n_rows) {
        union { __hip_bfloat16 h; short s; } u;
        u.s = f2bf(acc0[j][r]);
        H[(size_t)row0 * CDIM + col] = u.h;
      }
      int row1 = crow + 16 + r;
      if (row1 < n_rows) {
        union { __hip_bfloat16 h; short s; } u;
        u.s = f2bf(acc1[j][r]);
        H[(size_t)row1 * CDIM + col] = u.h;
      }
    }
  }
}

// ---------------------------------------------------------------- fused SpMM + ELU + add
// one wave per output row; lane handles channels [2*lane, 2*lane+1] (bf16 pair)
__global__ __launch_bounds__(256) void spmm_out_kernel(
    const int* __restrict__ rp1, const int2* __restrict__ ep1,
    const unsigned int* __restrict__ h1,
    const int* __restrict__ rp2, const int2* __restrict__ ep2,
    const unsigned int* __restrict__ h2,
    float* __restrict__ out, int n_r) {
  int wave = threadIdx.x >> 6;
  int lane = threadIdx.x & 63;
  int row = blockIdx.x * 4 + wave;
  if (row >= n_r) return;

  float ex[2], ey[2];
#pragma unroll
  for (int L = 0; L < 2; ++L) {
    const int* rp = L ? rp2 : rp1;
    const int2* ep = L ? ep2 : ep1;
    const unsigned int* h = L ? h2 : h1;
    float2 A0 = make_float2(0.f, 0.f), A1 = make_float2(0.f, 0.f);
    float2 A2 = make_float2(0.f, 0.f), A3 = make_float2(0.f, 0.f);
    int s = rp[row], e = rp[row + 1];
    int i = s;
    for (; i + 4 <= e; i += 4) {
      int2 e0 = ep[i], e1 = ep[i + 1], e2 = ep[i + 2], e3 = ep[i + 3];
      unsigned int p0 = h[(size_t)e0.x * 64 + lane];
      unsigned int p1 = h[(size_t)e1.x * 64 + lane];
      unsigned int p2 = h[(size_t)e2.x * 64 + lane];
      unsigned int p3 = h[(size_t)e3.x * 64 + lane];
      float v0 = __int_as_float(e0.y), v1 = __int_as_float(e1.y);
      float v2 = __int_as_float(e2.y), v3 = __int_as_float(e3.y);
      A0.x += v0 * __uint_as_float(p0 << 16);
      A0.y += v0 * __uint_as_float(p0 & 0xffff0000u);
      A1.x += v1 * __uint_as_float(p1 << 16);
      A1.y += v1 * __uint_as_float(p1 & 0xffff0000u);
      A2.x += v2 * __uint_as_float(p2 << 16);
      A2.y += v2 * __uint_as_float(p2 & 0xffff0000u);
      A3.x += v3 * __uint_as_float(p3 << 16);
      A3.y += v3 * __uint_as_float(p3 & 0xffff0000u);
    }
    for (; i < e; ++i) {
      int2 ev = ep[i];
      unsigned int p = h[(size_t)ev.x * 64 + lane];
      float v = __int_as_float(ev.y);
      A0.x += v * __uint_as_float(p << 16);
      A0.y += v * __uint_as_float(p & 0xffff0000u);
    }
    float sx = (A0.x + A1.x) + (A2.x + A3.x);
    float sy = (A0.y + A1.y) + (A2.y + A3.y);
    ex[L] = sx > 0.f ? sx : expm1f(sx);
    ey[L] = sy > 0.f ? sy : expm1f(sy);
  }

  float2 o = make_float2(ex[0] + ex[1], ey[0] + ey[1]);
  *(float2*)(out + (size_t)row * CDIM + 2 * lane) = o;
}

// ---------------------------------------------------------------- launch
extern "C" void kernel_launch(void* const* d_in, const int* in_sizes, int n_in,
                              void* d_out, int out_size, void* d_ws, size_t ws_size,
                              hipStream_t stream) {
  const float* x1  = (const float*)d_in[0];
  const float* x2  = (const float*)d_in[1];
  const float* W1  = (const float*)d_in[2];
  const float* W2  = (const float*)d_in[3];
  const float* v11 = (const float*)d_in[4];
  const float* v21 = (const float*)d_in[5];
  const int* r11   = (const int*)d_in[6];
  const int* c11   = (const int*)d_in[7];
  const int* r21   = (const int*)d_in[8];
  const int* c21   = (const int*)d_in[9];

  int n_r   = in_sizes[0] / CDIM;
  int n_rp1 = in_sizes[1] / CDIM;
  int nnz   = in_sizes[4];
  float* out = (float*)d_out;
  int nbins = (n_r + BIN_ROWS - 1) >> BIN_SHIFT;  // 196; must be <= MAX_BINS

  char* ws = (char*)d_ws;
  size_t off = 0;
  auto alloc = [&](size_t bytes) -> void* {
    void* p = ws + off;
    off = (off + bytes + 255) & ~(size_t)255;
    return p;
  };
  __hip_bfloat16* h1 = (__hip_bfloat16*)alloc((size_t)n_r * CDIM * 2);    // 25.6 MB
  __hip_bfloat16* h2 = (__hip_bfloat16*)alloc((size_t)n_rp1 * CDIM * 2);  // 51.2 MB
  __hip_bfloat16* Wt1 = (__hip_bfloat16*)alloc(CDIM * CDIM * 2);
  __hip_bfloat16* Wt2 = (__hip_bfloat16*)alloc(CDIM * CDIM * 2);
  int* rp1  = (int*)alloc(((size_t)n_r + 1) * 4);
  int* rp2  = (int*)alloc(((size_t)n_r + 1) * 4);
  int* bcnt     = (int*)alloc(2 * MAX_BINS * 4);
  int* bincur   = (int*)alloc(2 * MAX_BINS * 4);
  int* binstart = (int*)alloc(2 * (MAX_BINS + 1) * 4);
  int2* ep1 = (int2*)alloc((size_t)nnz * 8);            // 12.8 MB
  int2* ep2 = (int2*)alloc((size_t)nnz * 8);            // 12.8 MB
  int2* tmp1 = (int2*)alloc((size_t)nnz * 8);           // 12.8 MB
  int2* tmp2 = (int2*)alloc((size_t)nnz * 8);           // 12.8 MB
  (void)ws_size;  // ~129 MB of workspace

  hipMemsetAsync(bcnt, 0, 2 * MAX_BINS * 4, stream);

  int nb_e = (nnz + PCHUNK - 1) / PCHUNK;  // 391
  hist_bins<<<nb_e, 256, 0, stream>>>(r11, r21, bcnt, nnz);
  scan_bins<<<1, 256, 0, stream>>>(bcnt, binstart, bincur, nbins, nnz);

  partition_kernel<<<dim3(nb_e, 2), 256, 0, stream>>>(
      r11, c11, v11, r21, c21, v21, bincur, tmp1, tmp2, nnz);
  fill3_kernel<<<dim3(nbins, 2), 256, 0, stream>>>(
      tmp1, tmp2, binstart, ep1, ep2, rp1, rp2, n_r, nnz, nbins);

  prep_w<<<2, 256, 0, stream>>>(W1, W2, Wt1, Wt2);

  gemm_mfma<<<(n_r + 127) / 128, 256, 0, stream>>>(x1, Wt1, h1, n_r);
  gemm_mfma<<<(n_rp1 + 127) / 128, 256, 0, stream>>>(x2, Wt2, h2, n_rp1);

  spmm_out_kernel<<<(n_r + 3) / 4, 256, 0, stream>>>(
      rp1, ep1, (const unsigned int*)h1,
      rp2, ep2, (const unsigned int*)h2, out, n_r);
}

// Round 5
// 322.737 us; speedup vs baseline: 2.1213x; 1.0825x over previous
//
#include <hip/hip_runtime.h>
#include <hip/hip_bf16.h>

// Sizes (runtime): N_R = 100000, N_RP1 = 200000, NNZ = 1600000, C = 128
//
// Pipeline (6 launches):
//   1. memset bcnt
//   2. A: hist_bins blocks (391) + prep_w blocks (2)
//   3. scan_bins (1 block)
//   4. B: partition blocks (2x391) + gemm1 (782) + gemm2 (1563)   [overlap]
//   5. fill3 (196 x 2): per-bin LDS counting sort -> sequential ep writes + rp
//   6. spmm_out: half-wave per edge-list-half, 4ch/lane dwordx2 gather

#define CDIM 128
#define BIN_SHIFT 9            // 512 rows per bin
#define BIN_ROWS (1 << BIN_SHIFT)
#define MAX_BINS 256           // supports n_r <= 131072
#define PCHUNK 4096            // edges per hist/partition block
#define FCAP 9216              // LDS staging capacity (72KB); bins avg 8163 (+11.7 sigma)

typedef __attribute__((ext_vector_type(8))) short bf16x8;
typedef __attribute__((ext_vector_type(4))) float f32x4;

static __device__ __forceinline__ short f2bf(float f) {
  __hip_bfloat16 h = __float2bfloat16(f);
  union { __hip_bfloat16 h; short s; } u;
  u.h = h;
  return u.s;
}

// ---------------------------------------------------------------- A: hist + prep_w
__global__ __launch_bounds__(256) void hist_prep_kernel(
    const int* __restrict__ r1, const int* __restrict__ r2,
    int* __restrict__ bcnt, int nnz, int nhist,
    const float* __restrict__ W1, const float* __restrict__ W2,
    __hip_bfloat16* __restrict__ Wt1, __hip_bfloat16* __restrict__ Wt2) {
  __shared__ int c1[MAX_BINS], c2[MAX_BINS];
  int t = threadIdx.x;
  if ((int)blockIdx.x < nhist) {
    c1[t] = 0;
    c2[t] = 0;
    __syncthreads();
    int e0 = blockIdx.x * PCHUNK + t;
#pragma unroll
    for (int i = 0; i < 16; ++i) {
      int e = e0 + i * 256;
      if (e < nnz) {
        atomicAdd(&c1[r1[e] >> BIN_SHIFT], 1);
        atomicAdd(&c2[r2[e] >> BIN_SHIFT], 1);
      }
    }
    __syncthreads();
    if (c1[t]) atomicAdd(&bcnt[t], c1[t]);
    if (c2[t]) atomicAdd(&bcnt[MAX_BINS + t], c2[t]);
  } else {
    int wb = blockIdx.x - nhist;  // 0 or 1
    const float* W = wb ? W2 : W1;
    __hip_bfloat16* Wt = wb ? Wt2 : Wt1;
    for (int idx = t; idx < CDIM * CDIM; idx += 256) {
      int k = idx >> 7, n = idx & 127;
      union { __hip_bfloat16 h; short s; } u;
      u.s = f2bf(W[idx]);
      Wt[n * CDIM + k] = u.h;
    }
  }
}

// ---------------------------------------------------------------- bin scan (1 block)
__global__ __launch_bounds__(256) void scan_bins(
    const int* __restrict__ bcnt, int* __restrict__ binstart,
    int* __restrict__ bincur, int nbins, int nnz) {
  __shared__ int ws[4];
  int t = threadIdx.x, lane = t & 63, w = t >> 6;
  for (int L = 0; L < 2; ++L) {
    int v = (t < nbins) ? bcnt[L * MAX_BINS + t] : 0;
    int sc = v;
#pragma unroll
    for (int d = 1; d < 64; d <<= 1) {
      int u = __shfl_up(sc, d);
      if (lane >= d) sc += u;
    }
    if (lane == 63) ws[w] = sc;
    __syncthreads();
    int woff = 0;
    for (int i = 0; i < w; ++i) woff += ws[i];
    int excl = woff + sc - v;
    if (t < nbins) {
      binstart[L * (MAX_BINS + 1) + t] = excl;
      bincur[L * MAX_BINS + t] = excl;
    }
    if (t == 0) binstart[L * (MAX_BINS + 1) + nbins] = nnz;
    __syncthreads();
  }
}

// ---------------------------------------------------------------- B: partition + gemm
// partition: bin edges into tmp, bin-contiguous. Packed: x=(row_in_bin<<18)|col, y=val.
// gemm: H[row][col] = bf16( X[row][:] @ W[:][col] ), Wt bf16 [col][k], no LDS.
//   mfma_f32_16x16x32_bf16: A lane l: A[l&15][(l>>4)*8+e]; B: B[(l>>4)*8+e][l&15];
//   C/D: col=l&15, row=(l>>4)*4+reg.
__global__ __launch_bounds__(256) void part_gemm_kernel(
    const int* __restrict__ r1, const int* __restrict__ c1, const float* __restrict__ v1,
    const int* __restrict__ r2, const int* __restrict__ c2, const float* __restrict__ v2,
    int* __restrict__ bincur, int2* __restrict__ tmp1, int2* __restrict__ tmp2,
    int nnz, int npart,
    const float* __restrict__ x1, const __hip_bfloat16* __restrict__ Wt1,
    __hip_bfloat16* __restrict__ h1, int n_r, int ng1,
    const float* __restrict__ x2, const __hip_bfloat16* __restrict__ Wt2,
    __hip_bfloat16* __restrict__ h2, int n_rp1) {
  __shared__ int cnt[MAX_BINS], base[MAX_BINS], loff[MAX_BINS];
  int b = blockIdx.x;
  int t = threadIdx.x;

  if (b < 2 * npart) {
    // ---------------- partition ----------------
    int list = b >= npart;
    int pb = list ? b - npart : b;
    const int* r = list ? r2 : r1;
    const int* c = list ? c2 : c1;
    const float* v = list ? v2 : v1;
    int2* tmp = list ? tmp2 : tmp1;
    int* bcur = bincur + list * MAX_BINS;

    cnt[t] = 0;
    __syncthreads();
    int e0 = pb * PCHUNK + t;
    int rows[16];
#pragma unroll
    for (int i = 0; i < 16; ++i) {
      int e = e0 + i * 256;
      rows[i] = (e < nnz) ? r[e] : -1;
      if (rows[i] >= 0) atomicAdd(&cnt[rows[i] >> BIN_SHIFT], 1);
    }
    __syncthreads();
    {
      int n = cnt[t];
      base[t] = n ? atomicAdd(&bcur[t], n) : 0;
      loff[t] = 0;
    }
    __syncthreads();
#pragma unroll
    for (int i = 0; i < 16; ++i) {
      if (rows[i] >= 0) {
        int e = e0 + i * 256;
        int bin = rows[i] >> BIN_SHIFT;
        int o = atomicAdd(&loff[bin], 1);
        tmp[base[bin] + o] = make_int2(((rows[i] & (BIN_ROWS - 1)) << 18) | c[e],
                                       __float_as_int(v[e]));
      }
    }
    return;
  }

  // ---------------- gemm ----------------
  b -= 2 * npart;
  const float* X;
  const __hip_bfloat16* Wt;
  __hip_bfloat16* H;
  int n_rows, bb;
  if (b < ng1) { X = x1; Wt = Wt1; H = h1; n_rows = n_r; bb = b; }
  else         { X = x2; Wt = Wt2; H = h2; n_rows = n_rp1; bb = b - ng1; }

  int lane = t & 63, wave = t >> 6;
  int rbase = bb * 128 + wave * 32;
  int lrow = lane & 15;
  int kq = (lane >> 4) * 8;

  int r0 = rbase + lrow;
  int r1r = r0 + 16;
  bool in0 = r0 < n_rows;
  bool in1 = r1r < n_rows;

  f32x4 acc0[8], acc1[8];
#pragma unroll
  for (int j = 0; j < 8; ++j) {
    acc0[j] = (f32x4){0.f, 0.f, 0.f, 0.f};
    acc1[j] = (f32x4){0.f, 0.f, 0.f, 0.f};
  }

  const float* x0p = X + (size_t)r0 * CDIM + kq;
  const float* x1p = X + (size_t)r1r * CDIM + kq;

  for (int kk = 0; kk < CDIM; kk += 32) {
    bf16x8 a0 = (bf16x8)(short)0, a1 = (bf16x8)(short)0;
    if (in0) {
      float4 u = *(const float4*)(x0p + kk);
      float4 v = *(const float4*)(x0p + kk + 4);
      a0[0] = f2bf(u.x); a0[1] = f2bf(u.y); a0[2] = f2bf(u.z); a0[3] = f2bf(u.w);
      a0[4] = f2bf(v.x); a0[5] = f2bf(v.y); a0[6] = f2bf(v.z); a0[7] = f2bf(v.w);
    }
    if (in1) {
      float4 u = *(const float4*)(x1p + kk);
      float4 v = *(const float4*)(x1p + kk + 4);
      a1[0] = f2bf(u.x); a1[1] = f2bf(u.y); a1[2] = f2bf(u.z); a1[3] = f2bf(u.w);
      a1[4] = f2bf(v.x); a1[5] = f2bf(v.y); a1[6] = f2bf(v.z); a1[7] = f2bf(v.w);
    }
    int k = kk + kq;
#pragma unroll
    for (int j = 0; j < 8; ++j) {
      int col = j * 16 + lrow;
      bf16x8 bv = *(const bf16x8*)(Wt + (size_t)col * CDIM + k);
      acc0[j] = __builtin_amdgcn_mfma_f32_16x16x32_bf16(a0, bv, acc0[j], 0, 0, 0);
      acc1[j] = __builtin_amdgcn_mfma_f32_16x16x32_bf16(a1, bv, acc1[j], 0, 0, 0);
    }
  }

  int crow = rbase + (lane >> 4) * 4;
#pragma unroll
  for (int j = 0; j < 8; ++j) {
    int col = j * 16 + lrow;
#pragma unroll
    for (int rr = 0; rr < 4; ++rr) {
      int row0 = crow + rr;
      if (row0 < n_rows) {
        union { __hip_bfloat16 h; short s; } u;
        u.s = f2bf(acc0[j][rr]);
        H[(size_t)row0 * CDIM + col] = u.h;
      }
      int row1 = crow + 16 + rr;
      if (row1 < n_rows) {
        union { __hip_bfloat16 h; short s; } u;
        u.s = f2bf(acc1[j][rr]);
        H[(size_t)row1 * CDIM + col] = u.h;
      }
    }
  }
}

// ---------------------------------------------------------------- fill (per-bin counting sort)
__global__ __launch_bounds__(256) void fill3_kernel(
    const int2* __restrict__ tmp1, const int2* __restrict__ tmp2,
    const int* __restrict__ binstart,
    int2* __restrict__ ep1, int2* __restrict__ ep2,
    int* __restrict__ rp1, int* __restrict__ rp2,
    int n, int nnz, int nbins) {
  int L = blockIdx.y;
  const int2* tmp = L ? tmp2 : tmp1;
  int2* ep = L ? ep2 : ep1;
  int* rp = L ? rp2 : rp1;
  int bin = blockIdx.x;
  int bs = binstart[L * (MAX_BINS + 1) + bin];
  int be = binstart[L * (MAX_BINS + 1) + bin + 1];
  int count = be - bs;

  __shared__ int cnt[BIN_ROWS];
  __shared__ int wsum[4];
  __shared__ int2 outbuf[FCAP];
  int t = threadIdx.x, lane = t & 63, w = t >> 6;
  cnt[2 * t] = 0;
  cnt[2 * t + 1] = 0;
  __syncthreads();

  for (int p = bs + t; p < be; p += 256) {
    int rib = (unsigned)tmp[p].x >> 18;
    atomicAdd(&cnt[rib], 1);
  }
  __syncthreads();

  int a0 = cnt[2 * t], a1 = cnt[2 * t + 1];
  int pair = a0 + a1;
  int sc = pair;
#pragma unroll
  for (int d = 1; d < 64; d <<= 1) {
    int u = __shfl_up(sc, d);
    if (lane >= d) sc += u;
  }
  if (lane == 63) wsum[w] = sc;
  __syncthreads();
  int woff = 0;
  for (int i = 0; i < w; ++i) woff += wsum[i];
  int excl = woff + sc - pair;
  cnt[2 * t] = excl;
  cnt[2 * t + 1] = excl + a0;
  int row0 = (bin << BIN_SHIFT) + 2 * t;
  if (row0 < n) rp[row0] = bs + excl;
  if (row0 + 1 < n) rp[row0 + 1] = bs + excl + a0;
  if (bin == nbins - 1 && t == 0) rp[n] = nnz;
  __syncthreads();

  if (count <= FCAP) {
    for (int p = bs + t; p < be; p += 256) {
      int2 ev = tmp[p];
      int rib = (unsigned)ev.x >> 18;
      int slot = atomicAdd(&cnt[rib], 1);
      outbuf[slot] = make_int2(ev.x & 0x3FFFF, ev.y);
    }
    __syncthreads();
    for (int p = t; p < count; p += 256) ep[bs + p] = outbuf[p];
  } else {
    for (int p = bs + t; p < be; p += 256) {
      int2 ev = tmp[p];
      int rib = (unsigned)ev.x >> 18;
      int slot = atomicAdd(&cnt[rib], 1);
      ep[bs + slot] = make_int2(ev.x & 0x3FFFF, ev.y);
    }
  }
}

// ---------------------------------------------------------------- fused SpMM + ELU + add
// wave per row; half-wave (32 lanes) per half of the edge list; lane = 4 channels
// via one dwordx2 gather (half-wave covers the full 256B h row, coalesced).
__global__ __launch_bounds__(256) void spmm_out_kernel(
    const int* __restrict__ rp1, const int2* __restrict__ ep1,
    const uint2* __restrict__ h1,
    const int* __restrict__ rp2, const int2* __restrict__ ep2,
    const uint2* __restrict__ h2,
    float* __restrict__ out, int n_r) {
  int wave = threadIdx.x >> 6;
  int lane = threadIdx.x & 63;
  int half = lane >> 5;
  int l32 = lane & 31;
  int row = blockIdx.x * 4 + wave;
  if (row >= n_r) return;

  float4 res = make_float4(0.f, 0.f, 0.f, 0.f);
#pragma unroll
  for (int L = 0; L < 2; ++L) {
    const int* rp = L ? rp2 : rp1;
    const int2* ep = L ? ep2 : ep1;
    const uint2* h = L ? h2 : h1;
    int s = rp[row], e = rp[row + 1];
    int h0n = (e - s + 1) >> 1;
    int beg = s + (half ? h0n : 0);
    int end = half ? e : s + h0n;

    float a0 = 0.f, a1 = 0.f, a2 = 0.f, a3 = 0.f;
    float b0 = 0.f, b1 = 0.f, b2 = 0.f, b3 = 0.f;
    int i = beg;
    for (; i + 1 < end; i += 2) {
      int2 ea = ep[i];
      int2 eb = ep[i + 1];
      uint2 pa = h[(size_t)(unsigned)ea.x * 32 + l32];
      uint2 pb = h[(size_t)(unsigned)eb.x * 32 + l32];
      float va = __int_as_float(ea.y);
      float vb = __int_as_float(eb.y);
      a0 += va * __uint_as_float(pa.x << 16);
      a1 += va * __uint_as_float(pa.x & 0xffff0000u);
      a2 += va * __uint_as_float(pa.y << 16);
      a3 += va * __uint_as_float(pa.y & 0xffff0000u);
      b0 += vb * __uint_as_float(pb.x << 16);
      b1 += vb * __uint_as_float(pb.x & 0xffff0000u);
      b2 += vb * __uint_as_float(pb.y << 16);
      b3 += vb * __uint_as_float(pb.y & 0xffff0000u);
    }
    if (i < end) {
      int2 ea = ep[i];
      uint2 pa = h[(size_t)(unsigned)ea.x * 32 + l32];
      float va = __int_as_float(ea.y);
      a0 += va * __uint_as_float(pa.x << 16);
      a1 += va * __uint_as_float(pa.x & 0xffff0000u);
      a2 += va * __uint_as_float(pa.y << 16);
      a3 += va * __uint_as_float(pa.y & 0xffff0000u);
    }
    float s0 = a0 + b0, s1 = a1 + b1, s2 = a2 + b2, s3 = a3 + b3;
    s0 += __shfl_xor(s0, 32);
    s1 += __shfl_xor(s1, 32);
    s2 += __shfl_xor(s2, 32);
    s3 += __shfl_xor(s3, 32);
    s0 = s0 > 0.f ? s0 : expm1f(s0);
    s1 = s1 > 0.f ? s1 : expm1f(s1);
    s2 = s2 > 0.f ? s2 : expm1f(s2);
    s3 = s3 > 0.f ? s3 : expm1f(s3);
    res.x += s0; res.y += s1; res.z += s2; res.w += s3;
  }
  if (!half) *(float4*)(out + (size_t)row * CDIM + l32 * 4) = res;
}

// ---------------------------------------------------------------- launch
extern "C" void kernel_launch(void* const* d_in, const int* in_sizes, int n_in,
                              void* d_out, int out_size, void* d_ws, size_t ws_size,
                              hipStream_t stream) {
  const float* x1  = (const float*)d_in[0];
  const float* x2  = (const float*)d_in[1];
  const float* W1  = (const float*)d_in[2];
  const float* W2  = (const float*)d_in[3];
  const float* v11 = (const float*)d_in[4];
  const float* v21 = (const float*)d_in[5];
  const int* r11   = (const int*)d_in[6];
  const int* c11   = (const int*)d_in[7];
  const int* r21   = (const int*)d_in[8];
  const int* c21   = (const int*)d_in[9];

  int n_r   = in_sizes[0] / CDIM;
  int n_rp1 = in_sizes[1] / CDIM;
  int nnz   = in_sizes[4];
  float* out = (float*)d_out;
  int nbins = (n_r + BIN_ROWS - 1) >> BIN_SHIFT;  // 196; must be <= MAX_BINS

  char* ws = (char*)d_ws;
  size_t off = 0;
  auto alloc = [&](size_t bytes) -> void* {
    void* p = ws + off;
    off = (off + bytes + 255) & ~(size_t)255;
    return p;
  };
  __hip_bfloat16* h1 = (__hip_bfloat16*)alloc((size_t)n_r * CDIM * 2);    // 25.6 MB
  __hip_bfloat16* h2 = (__hip_bfloat16*)alloc((size_t)n_rp1 * CDIM * 2);  // 51.2 MB
  __hip_bfloat16* Wt1 = (__hip_bfloat16*)alloc(CDIM * CDIM * 2);
  __hip_bfloat16* Wt2 = (__hip_bfloat16*)alloc(CDIM * CDIM * 2);
  int* rp1  = (int*)alloc(((size_t)n_r + 1) * 4);
  int* rp2  = (int*)alloc(((size_t)n_r + 1) * 4);
  int* bcnt     = (int*)alloc(2 * MAX_BINS * 4);
  int* bincur   = (int*)alloc(2 * MAX_BINS * 4);
  int* binstart = (int*)alloc(2 * (MAX_BINS + 1) * 4);
  int2* ep1 = (int2*)alloc((size_t)nnz * 8);            // 12.8 MB
  int2* ep2 = (int2*)alloc((size_t)nnz * 8);            // 12.8 MB
  int2* tmp1 = (int2*)alloc((size_t)nnz * 8);           // 12.8 MB
  int2* tmp2 = (int2*)alloc((size_t)nnz * 8);           // 12.8 MB
  (void)ws_size;  // ~129 MB of workspace

  hipMemsetAsync(bcnt, 0, 2 * MAX_BINS * 4, stream);

  int npart = (nnz + PCHUNK - 1) / PCHUNK;  // 391
  int ng1 = (n_r + 127) / 128;              // 782
  int ng2 = (n_rp1 + 127) / 128;            // 1563

  hist_prep_kernel<<<npart + 2, 256, 0, stream>>>(
      r11, r21, bcnt, nnz, npart, W1, W2, Wt1, Wt2);
  scan_bins<<<1, 256, 0, stream>>>(bcnt, binstart, bincur, nbins, nnz);

  part_gemm_kernel<<<2 * npart + ng1 + ng2, 256, 0, stream>>>(
      r11, c11, v11, r21, c21, v21, bincur, tmp1, tmp2, nnz, npart,
      x1, Wt1, h1, n_r, ng1, x2, Wt2, h2, n_rp1);

  fill3_kernel<<<dim3(nbins, 2), 256, 0, stream>>>(
      tmp1, tmp2, binstart, ep1, ep2, rp1, rp2, n_r, nnz, nbins);

  spmm_out_kernel<<<(n_r + 3) / 4, 256, 0, stream>>>(
      rp1, ep1, (const uint2*)h1,
      rp2, ep2, (const uint2*)h2, out, n_r);
}

// Round 6
// 310.023 us; speedup vs baseline: 2.2083x; 1.0410x over previous
//
#include <hip/hip_runtime.h>
#include <hip/hip_bf16.h>

// Sizes (runtime): N_R = 100000, N_RP1 = 200000, NNZ = 1600000, C = 128
//
// Pipeline (7 dispatches):
//   1. memset bcnt
//   2. hist_prep: per-block LDS bin histogram (bin = row>>9) + Wt = bf16(W^T)
//   3. scan_bins (1 block) -> binstart, bincur
//   4. partition: per-block counting sort by bin in LDS -> tmp writes in
//      sorted order (each store instr touches ~4 lines, not ~55)
//   5. gemm_both: h = bf16(X @ W) via mfma_f32_16x16x32_bf16, LDS-free
//   6. fill3: one block per bin: LDS counting sort by row -> sequential ep + rp
//   7. spmm_out: wave/row, half-wave per edge-list half, 4ch/lane dwordx2

#define CDIM 128
#define BIN_SHIFT 9            // 512 rows per bin
#define BIN_ROWS (1 << BIN_SHIFT)
#define MAX_BINS 256           // supports n_r <= 131072
#define PCHUNK 4096            // edges per hist/partition block
#define FCAP 9216              // fill3 LDS staging (72KB); bins avg 8163 (+11.7 sigma)

typedef __attribute__((ext_vector_type(8))) short bf16x8;
typedef __attribute__((ext_vector_type(4))) float f32x4;

static __device__ __forceinline__ short f2bf(float f) {
  __hip_bfloat16 h = __float2bfloat16(f);
  union { __hip_bfloat16 h; short s; } u;
  u.h = h;
  return u.s;
}

// ---------------------------------------------------------------- hist + prep_w
__global__ __launch_bounds__(256) void hist_prep_kernel(
    const int* __restrict__ r1, const int* __restrict__ r2,
    int* __restrict__ bcnt, int nnz, int nhist,
    const float* __restrict__ W1, const float* __restrict__ W2,
    __hip_bfloat16* __restrict__ Wt1, __hip_bfloat16* __restrict__ Wt2) {
  __shared__ int c1[MAX_BINS], c2[MAX_BINS];
  int t = threadIdx.x;
  if ((int)blockIdx.x < nhist) {
    c1[t] = 0;
    c2[t] = 0;
    __syncthreads();
    int e0 = blockIdx.x * PCHUNK + t;
#pragma unroll
    for (int i = 0; i < 16; ++i) {
      int e = e0 + i * 256;
      if (e < nnz) {
        atomicAdd(&c1[r1[e] >> BIN_SHIFT], 1);
        atomicAdd(&c2[r2[e] >> BIN_SHIFT], 1);
      }
    }
    __syncthreads();
    if (c1[t]) atomicAdd(&bcnt[t], c1[t]);
    if (c2[t]) atomicAdd(&bcnt[MAX_BINS + t], c2[t]);
  } else {
    int wb = blockIdx.x - nhist;  // 0 or 1
    const float* W = wb ? W2 : W1;
    __hip_bfloat16* Wt = wb ? Wt2 : Wt1;
    for (int idx = t; idx < CDIM * CDIM; idx += 256) {
      int k = idx >> 7, n = idx & 127;
      union { __hip_bfloat16 h; short s; } u;
      u.s = f2bf(W[idx]);
      Wt[n * CDIM + k] = u.h;
    }
  }
}

// ---------------------------------------------------------------- bin scan (1 block)
__global__ __launch_bounds__(256) void scan_bins(
    const int* __restrict__ bcnt, int* __restrict__ binstart,
    int* __restrict__ bincur, int nbins, int nnz) {
  __shared__ int ws[4];
  int t = threadIdx.x, lane = t & 63, w = t >> 6;
  for (int L = 0; L < 2; ++L) {
    int v = (t < nbins) ? bcnt[L * MAX_BINS + t] : 0;
    int sc = v;
#pragma unroll
    for (int d = 1; d < 64; d <<= 1) {
      int u = __shfl_up(sc, d);
      if (lane >= d) sc += u;
    }
    if (lane == 63) ws[w] = sc;
    __syncthreads();
    int woff = 0;
    for (int i = 0; i < w; ++i) woff += ws[i];
    int excl = woff + sc - v;
    if (t < nbins) {
      binstart[L * (MAX_BINS + 1) + t] = excl;
      bincur[L * MAX_BINS + t] = excl;
    }
    if (t == 0) binstart[L * (MAX_BINS + 1) + nbins] = nnz;
    __syncthreads();
  }
}

// ---------------------------------------------------------------- partition (LDS-sorted)
// Per-block counting sort by bin into LDS, then write tmp in sorted order so
// consecutive lanes write consecutive addresses (runs of ~16 edges per bin).
// Packed entry: x = (row_in_bin << 18) | col, y = val bits.
__global__ __launch_bounds__(256) void partition_kernel(
    const int* __restrict__ r1, const int* __restrict__ c1, const float* __restrict__ v1,
    const int* __restrict__ r2, const int* __restrict__ c2, const float* __restrict__ v2,
    int* __restrict__ bincur, int2* __restrict__ tmp1, int2* __restrict__ tmp2,
    int nnz, int npart) {
  __shared__ int lbase[MAX_BINS];   // counts, then local exclusive scan
  __shared__ int gbase[MAX_BINS];   // global base per bin for this block
  __shared__ int loff[MAX_BINS];
  __shared__ int wsum[4];
  __shared__ int2 sbuf[PCHUNK];
  __shared__ unsigned char binof[PCHUNK];

  int b = blockIdx.x;
  int list = b >= npart;
  int pb = list ? b - npart : b;
  const int* r = list ? r2 : r1;
  const int* c = list ? c2 : c1;
  const float* v = list ? v2 : v1;
  int2* tmp = list ? tmp2 : tmp1;
  int* bcur = bincur + list * MAX_BINS;

  int t = threadIdx.x, lane = t & 63, w = t >> 6;
  lbase[t] = 0;
  __syncthreads();

  int e0 = pb * PCHUNK + t;
  int total = nnz - pb * PCHUNK;
  if (total > PCHUNK) total = PCHUNK;

  int rows[16];
#pragma unroll
  for (int i = 0; i < 16; ++i) {
    int e = e0 + i * 256;
    rows[i] = (e < nnz) ? r[e] : -1;
    if (rows[i] >= 0) atomicAdd(&lbase[rows[i] >> BIN_SHIFT], 1);
  }
  __syncthreads();

  // exclusive scan of counts (1 elem/thread over 256 = 4 waves)
  int cv = lbase[t];
  int sc = cv;
#pragma unroll
  for (int d = 1; d < 64; d <<= 1) {
    int u = __shfl_up(sc, d);
    if (lane >= d) sc += u;
  }
  if (lane == 63) wsum[w] = sc;
  __syncthreads();
  int woff = 0;
  for (int i = 0; i < w; ++i) woff += wsum[i];
  int excl = woff + sc - cv;
  lbase[t] = excl;
  gbase[t] = cv ? atomicAdd(&bcur[t], cv) : 0;
  loff[t] = 0;
  __syncthreads();

  // place into LDS sorted by bin
#pragma unroll
  for (int i = 0; i < 16; ++i) {
    if (rows[i] >= 0) {
      int e = e0 + i * 256;
      int bin = rows[i] >> BIN_SHIFT;
      int o = atomicAdd(&loff[bin], 1);
      int pos = lbase[bin] + o;
      sbuf[pos] = make_int2(((rows[i] & (BIN_ROWS - 1)) << 18) | c[e],
                            __float_as_int(v[e]));
      binof[pos] = (unsigned char)bin;
    }
  }
  __syncthreads();

  // sorted write-out: consecutive p -> consecutive dst within each bin run
  for (int p = t; p < total; p += 256) {
    int bin = binof[p];
    tmp[gbase[bin] + (p - lbase[bin])] = sbuf[p];
  }
}

// ---------------------------------------------------------------- GEMM (both)
// H[row][col] = bf16( X[row][:] @ W[:][col] ), Wt bf16 [col][k], no LDS.
//   mfma_f32_16x16x32_bf16: A lane l: A[l&15][(l>>4)*8+e]; B: B[(l>>4)*8+e][l&15];
//   C/D: col=l&15, row=(l>>4)*4+reg.
__global__ __launch_bounds__(256) void gemm_both_kernel(
    const float* __restrict__ x1, const __hip_bfloat16* __restrict__ Wt1,
    __hip_bfloat16* __restrict__ h1, int n_r, int ng1,
    const float* __restrict__ x2, const __hip_bfloat16* __restrict__ Wt2,
    __hip_bfloat16* __restrict__ h2, int n_rp1) {
  int b = blockIdx.x;
  const float* X;
  const __hip_bfloat16* Wt;
  __hip_bfloat16* H;
  int n_rows, bb;
  if (b < ng1) { X = x1; Wt = Wt1; H = h1; n_rows = n_r; bb = b; }
  else         { X = x2; Wt = Wt2; H = h2; n_rows = n_rp1; bb = b - ng1; }

  int t = threadIdx.x;
  int lane = t & 63, wave = t >> 6;
  int rbase = bb * 128 + wave * 32;
  int lrow = lane & 15;
  int kq = (lane >> 4) * 8;

  int r0 = rbase + lrow;
  int r1r = r0 + 16;
  bool in0 = r0 < n_rows;
  bool in1 = r1r < n_rows;

  f32x4 acc0[8], acc1[8];
#pragma unroll
  for (int j = 0; j < 8; ++j) {
    acc0[j] = (f32x4){0.f, 0.f, 0.f, 0.f};
    acc1[j] = (f32x4){0.f, 0.f, 0.f, 0.f};
  }

  const float* x0p = X + (size_t)r0 * CDIM + kq;
  const float* x1p = X + (size_t)r1r * CDIM + kq;

  for (int kk = 0; kk < CDIM; kk += 32) {
    bf16x8 a0 = (bf16x8)(short)0, a1 = (bf16x8)(short)0;
    if (in0) {
      float4 u = *(const float4*)(x0p + kk);
      float4 vv = *(const float4*)(x0p + kk + 4);
      a0[0] = f2bf(u.x); a0[1] = f2bf(u.y); a0[2] = f2bf(u.z); a0[3] = f2bf(u.w);
      a0[4] = f2bf(vv.x); a0[5] = f2bf(vv.y); a0[6] = f2bf(vv.z); a0[7] = f2bf(vv.w);
    }
    if (in1) {
      float4 u = *(const float4*)(x1p + kk);
      float4 vv = *(const float4*)(x1p + kk + 4);
      a1[0] = f2bf(u.x); a1[1] = f2bf(u.y); a1[2] = f2bf(u.z); a1[3] = f2bf(u.w);
      a1[4] = f2bf(vv.x); a1[5] = f2bf(vv.y); a1[6] = f2bf(vv.z); a1[7] = f2bf(vv.w);
    }
    int k = kk + kq;
#pragma unroll
    for (int j = 0; j < 8; ++j) {
      int col = j * 16 + lrow;
      bf16x8 bv = *(const bf16x8*)(Wt + (size_t)col * CDIM + k);
      acc0[j] = __builtin_amdgcn_mfma_f32_16x16x32_bf16(a0, bv, acc0[j], 0, 0, 0);
      acc1[j] = __builtin_amdgcn_mfma_f32_16x16x32_bf16(a1, bv, acc1[j], 0, 0, 0);
    }
  }

  int crow = rbase + (lane >> 4) * 4;
#pragma unroll
  for (int j = 0; j < 8; ++j) {
    int col = j * 16 + lrow;
#pragma unroll
    for (int rr = 0; rr < 4; ++rr) {
      int row0 = crow + rr;
      if (row0 < n_rows) {
        union { __hip_bfloat16 h; short s; } u;
        u.s = f2bf(acc0[j][rr]);
        H[(size_t)row0 * CDIM + col] = u.h;
      }
      int row1 = crow + 16 + rr;
      if (row1 < n_rows) {
        union { __hip_bfloat16 h; short s; } u;
        u.s = f2bf(acc1[j][rr]);
        H[(size_t)row1 * CDIM + col] = u.h;
      }
    }
  }
}

// ---------------------------------------------------------------- fill (per-bin counting sort)
__global__ __launch_bounds__(256) void fill3_kernel(
    const int2* __restrict__ tmp1, const int2* __restrict__ tmp2,
    const int* __restrict__ binstart,
    int2* __restrict__ ep1, int2* __restrict__ ep2,
    int* __restrict__ rp1, int* __restrict__ rp2,
    int n, int nnz, int nbins) {
  int L = blockIdx.y;
  const int2* tmp = L ? tmp2 : tmp1;
  int2* ep = L ? ep2 : ep1;
  int* rp = L ? rp2 : rp1;
  int bin = blockIdx.x;
  int bs = binstart[L * (MAX_BINS + 1) + bin];
  int be = binstart[L * (MAX_BINS + 1) + bin + 1];
  int count = be - bs;

  __shared__ int cnt[BIN_ROWS];
  __shared__ int wsum[4];
  __shared__ int2 outbuf[FCAP];
  int t = threadIdx.x, lane = t & 63, w = t >> 6;
  cnt[2 * t] = 0;
  cnt[2 * t + 1] = 0;
  __syncthreads();

  for (int p = bs + t; p < be; p += 256) {
    int rib = (unsigned)tmp[p].x >> 18;
    atomicAdd(&cnt[rib], 1);
  }
  __syncthreads();

  int a0 = cnt[2 * t], a1 = cnt[2 * t + 1];
  int pair = a0 + a1;
  int sc = pair;
#pragma unroll
  for (int d = 1; d < 64; d <<= 1) {
    int u = __shfl_up(sc, d);
    if (lane >= d) sc += u;
  }
  if (lane == 63) wsum[w] = sc;
  __syncthreads();
  int woff = 0;
  for (int i = 0; i < w; ++i) woff += wsum[i];
  int excl = woff + sc - pair;
  cnt[2 * t] = excl;
  cnt[2 * t + 1] = excl + a0;
  int row0 = (bin << BIN_SHIFT) + 2 * t;
  if (row0 < n) rp[row0] = bs + excl;
  if (row0 + 1 < n) rp[row0 + 1] = bs + excl + a0;
  if (bin == nbins - 1 && t == 0) rp[n] = nnz;
  __syncthreads();

  if (count <= FCAP) {
    for (int p = bs + t; p < be; p += 256) {
      int2 ev = tmp[p];
      int rib = (unsigned)ev.x >> 18;
      int slot = atomicAdd(&cnt[rib], 1);
      outbuf[slot] = make_int2(ev.x & 0x3FFFF, ev.y);
    }
    __syncthreads();
    for (int p = t; p < count; p += 256) ep[bs + p] = outbuf[p];
  } else {
    for (int p = bs + t; p < be; p += 256) {
      int2 ev = tmp[p];
      int rib = (unsigned)ev.x >> 18;
      int slot = atomicAdd(&cnt[rib], 1);
      ep[bs + slot] = make_int2(ev.x & 0x3FFFF, ev.y);
    }
  }
}

// ---------------------------------------------------------------- fused SpMM + ELU + add
// wave per row; half-wave (32 lanes) per half of the edge list; lane = 4 channels
// via one dwordx2 gather (half-wave covers the full 256B h row, coalesced).
__global__ __launch_bounds__(256) void spmm_out_kernel(
    const int* __restrict__ rp1, const int2* __restrict__ ep1,
    const uint2* __restrict__ h1,
    const int* __restrict__ rp2, const int2* __restrict__ ep2,
    const uint2* __restrict__ h2,
    float* __restrict__ out, int n_r) {
  int wave = threadIdx.x >> 6;
  int lane = threadIdx.x & 63;
  int half = lane >> 5;
  int l32 = lane & 31;
  int row = blockIdx.x * 4 + wave;
  if (row >= n_r) return;

  float4 res = make_float4(0.f, 0.f, 0.f, 0.f);
#pragma unroll
  for (int L = 0; L < 2; ++L) {
    const int* rp = L ? rp2 : rp1;
    const int2* ep = L ? ep2 : ep1;
    const uint2* h = L ? h2 : h1;
    int s = rp[row], e = rp[row + 1];
    int h0n = (e - s + 1) >> 1;
    int beg = s + (half ? h0n : 0);
    int end = half ? e : s + h0n;

    float a0 = 0.f, a1 = 0.f, a2 = 0.f, a3 = 0.f;
    float b0 = 0.f, b1 = 0.f, b2 = 0.f, b3 = 0.f;
    int i = beg;
    for (; i + 1 < end; i += 2) {
      int2 ea = ep[i];
      int2 eb = ep[i + 1];
      uint2 pa = h[(size_t)(unsigned)ea.x * 32 + l32];
      uint2 pb = h[(size_t)(unsigned)eb.x * 32 + l32];
      float va = __int_as_float(ea.y);
      float vb = __int_as_float(eb.y);
      a0 += va * __uint_as_float(pa.x << 16);
      a1 += va * __uint_as_float(pa.x & 0xffff0000u);
      a2 += va * __uint_as_float(pa.y << 16);
      a3 += va * __uint_as_float(pa.y & 0xffff0000u);
      b0 += vb * __uint_as_float(pb.x << 16);
      b1 += vb * __uint_as_float(pb.x & 0xffff0000u);
      b2 += vb * __uint_as_float(pb.y << 16);
      b3 += vb * __uint_as_float(pb.y & 0xffff0000u);
    }
    if (i < end) {
      int2 ea = ep[i];
      uint2 pa = h[(size_t)(unsigned)ea.x * 32 + l32];
      float va = __int_as_float(ea.y);
      a0 += va * __uint_as_float(pa.x << 16);
      a1 += va * __uint_as_float(pa.x & 0xffff0000u);
      a2 += va * __uint_as_float(pa.y << 16);
      a3 += va * __uint_as_float(pa.y & 0xffff0000u);
    }
    float s0 = a0 + b0, s1 = a1 + b1, s2 = a2 + b2, s3 = a3 + b3;
    s0 += __shfl_xor(s0, 32);
    s1 += __shfl_xor(s1, 32);
    s2 += __shfl_xor(s2, 32);
    s3 += __shfl_xor(s3, 32);
    s0 = s0 > 0.f ? s0 : expm1f(s0);
    s1 = s1 > 0.f ? s1 : expm1f(s1);
    s2 = s2 > 0.f ? s2 : expm1f(s2);
    s3 = s3 > 0.f ? s3 : expm1f(s3);
    res.x += s0; res.y += s1; res.z += s2; res.w += s3;
  }
  if (!half) *(float4*)(out + (size_t)row * CDIM + l32 * 4) = res;
}

// ---------------------------------------------------------------- launch
extern "C" void kernel_launch(void* const* d_in, const int* in_sizes, int n_in,
                              void* d_out, int out_size, void* d_ws, size_t ws_size,
                              hipStream_t stream) {
  const float* x1  = (const float*)d_in[0];
  const float* x2  = (const float*)d_in[1];
  const float* W1  = (const float*)d_in[2];
  const float* W2  = (const float*)d_in[3];
  const float* v11 = (const float*)d_in[4];
  const float* v21 = (const float*)d_in[5];
  const int* r11   = (const int*)d_in[6];
  const int* c11   = (const int*)d_in[7];
  const int* r21   = (const int*)d_in[8];
  const int* c21   = (const int*)d_in[9];

  int n_r   = in_sizes[0] / CDIM;
  int n_rp1 = in_sizes[1] / CDIM;
  int nnz   = in_sizes[4];
  float* out = (float*)d_out;
  int nbins = (n_r + BIN_ROWS - 1) >> BIN_SHIFT;  // 196; must be <= MAX_BINS

  char* ws = (char*)d_ws;
  size_t off = 0;
  auto alloc = [&](size_t bytes) -> void* {
    void* p = ws + off;
    off = (off + bytes + 255) & ~(size_t)255;
    return p;
  };
  __hip_bfloat16* h1 = (__hip_bfloat16*)alloc((size_t)n_r * CDIM * 2);    // 25.6 MB
  __hip_bfloat16* h2 = (__hip_bfloat16*)alloc((size_t)n_rp1 * CDIM * 2);  // 51.2 MB
  __hip_bfloat16* Wt1 = (__hip_bfloat16*)alloc(CDIM * CDIM * 2);
  __hip_bfloat16* Wt2 = (__hip_bfloat16*)alloc(CDIM * CDIM * 2);
  int* rp1  = (int*)alloc(((size_t)n_r + 1) * 4);
  int* rp2  = (int*)alloc(((size_t)n_r + 1) * 4);
  int* bcnt     = (int*)alloc(2 * MAX_BINS * 4);
  int* bincur   = (int*)alloc(2 * MAX_BINS * 4);
  int* binstart = (int*)alloc(2 * (MAX_BINS + 1) * 4);
  int2* ep1 = (int2*)alloc((size_t)nnz * 8);            // 12.8 MB
  int2* ep2 = (int2*)alloc((size_t)nnz * 8);            // 12.8 MB
  int2* tmp1 = (int2*)alloc((size_t)nnz * 8);           // 12.8 MB
  int2* tmp2 = (int2*)alloc((size_t)nnz * 8);           // 12.8 MB
  (void)ws_size;  // ~129 MB of workspace

  hipMemsetAsync(bcnt, 0, 2 * MAX_BINS * 4, stream);

  int npart = (nnz + PCHUNK - 1) / PCHUNK;  // 391
  int ng1 = (n_r + 127) / 128;              // 782
  int ng2 = (n_rp1 + 127) / 128;            // 1563

  hist_prep_kernel<<<npart + 2, 256, 0, stream>>>(
      r11, r21, bcnt, nnz, npart, W1, W2, Wt1, Wt2);
  scan_bins<<<1, 256, 0, stream>>>(bcnt, binstart, bincur, nbins, nnz);

  partition_kernel<<<2 * npart, 256, 0, stream>>>(
      r11, c11, v11, r21, c21, v21, bincur, tmp1, tmp2, nnz, npart);

  gemm_both_kernel<<<ng1 + ng2, 256, 0, stream>>>(
      x1, Wt1, h1, n_r, ng1, x2, Wt2, h2, n_rp1);

  fill3_kernel<<<dim3(nbins, 2), 256, 0, stream>>>(
      tmp1, tmp2, binstart, ep1, ep2, rp1, rp2, n_r, nnz, nbins);

  spmm_out_kernel<<<(n_r + 3) / 4, 256, 0, stream>>>(
      rp1, ep1, (const uint2*)h1,
      rp2, ep2, (const uint2*)h2, out, n_r);
}

// Round 8
// 278.433 us; speedup vs baseline: 2.4588x; 1.1135x over previous
//
#include <hip/hip_runtime.h>
#include <hip/hip_bf16.h>

// Sizes (runtime): N_R = 100000, N_RP1 = 200000, NNZ = 1600000, C = 128
//
// Pipeline (5 dispatches):
//   1. memset bincur (bin cursors) to 0
//   2. part_prep: bin edges by row>>9 into slack-strided tmp regions
//      (bin b owns [b*bcap, (b+1)*bcap)); per-block LDS counting sort by bin
//      so tmp writes are sorted runs. +2 blocks convert W -> bf16 W^T.
//   3. fill3: one block per (bin,list): LDS counting sort by row ->
//      sequential ep writes into the bin's region; emits rs[]/re[] per row.
//   4. gemm_both: h = bf16(X @ W) via mfma_f32_16x16x32_bf16 (LDS-free).
//      Runs RIGHT BEFORE spmm so h (77 MB) stays hot in the 256MB L3.
//   5. spmm_out: 16-lane group per row; lane = 8 channels via one dwordx4
//      gather (h row = 16 uint4); f32x2 packed accumulate; __expf ELU.

#define CDIM 128
#define BIN_SHIFT 9            // 512 rows per bin
#define BIN_ROWS (1 << BIN_SHIFT)
#define MAX_BINS 256           // supports n_r <= 131072
#define PCHUNK 4096            // edges per partition block
#define FCAP 9216              // fill3 LDS staging capacity (72KB)

typedef __attribute__((ext_vector_type(8))) short bf16x8;
typedef __attribute__((ext_vector_type(4))) float f32x4;
typedef __attribute__((ext_vector_type(2))) float f32x2;

static __device__ __forceinline__ short f2bf(float f) {
  __hip_bfloat16 h = __float2bfloat16(f);
  union { __hip_bfloat16 h; short s; } u;
  u.h = h;
  return u.s;
}

static __device__ __forceinline__ f32x2 up2(unsigned u) {
  return f32x2{__uint_as_float(u << 16), __uint_as_float(u & 0xffff0000u)};
}

static __device__ __forceinline__ float elu1(float x) {
  return x > 0.f ? x : __expf(x) - 1.f;
}

// ---------------------------------------------------------------- partition + prep_w
// Slack bins: bin b region = [b*bcap, b*bcap + bincur[b]); cursors zero-init.
// Packed entry: x = (row_in_bin << 18) | col, y = val bits.
__global__ __launch_bounds__(256) void part_prep_kernel(
    const int* __restrict__ r1, const int* __restrict__ c1, const float* __restrict__ v1,
    const int* __restrict__ r2, const int* __restrict__ c2, const float* __restrict__ v2,
    int* __restrict__ bincur, int2* __restrict__ tmp1, int2* __restrict__ tmp2,
    int nnz, int npart, int bcap,
    const float* __restrict__ W1, const float* __restrict__ W2,
    __hip_bfloat16* __restrict__ Wt1, __hip_bfloat16* __restrict__ Wt2) {
  int b = blockIdx.x;
  int t = threadIdx.x;
  if (b >= 2 * npart) {
    // ---- prep_w (2 blocks) ----
    int wb = b - 2 * npart;
    const float* W = wb ? W2 : W1;
    __hip_bfloat16* Wt = wb ? Wt2 : Wt1;
    for (int idx = t; idx < CDIM * CDIM; idx += 256) {
      int k = idx >> 7, n = idx & 127;
      union { __hip_bfloat16 h; short s; } u;
      u.s = f2bf(W[idx]);
      Wt[n * CDIM + k] = u.h;
    }
    return;
  }

  __shared__ int lbase[MAX_BINS];   // counts, then local exclusive scan
  __shared__ int gofs[MAX_BINS];    // global within-bin offset for this block
  __shared__ int loff[MAX_BINS];
  __shared__ int wsum[4];
  __shared__ int2 sbuf[PCHUNK];
  __shared__ unsigned char binof[PCHUNK];

  int list = b >= npart;
  int pb = list ? b - npart : b;
  const int* r = list ? r2 : r1;
  const int* c = list ? c2 : c1;
  const float* v = list ? v2 : v1;
  int2* tmp = list ? tmp2 : tmp1;
  int* bcur = bincur + list * MAX_BINS;

  int lane = t & 63, w = t >> 6;
  lbase[t] = 0;
  __syncthreads();

  int e0 = pb * PCHUNK + t;
  int total = nnz - pb * PCHUNK;
  if (total > PCHUNK) total = PCHUNK;

  int rows[16];
#pragma unroll
  for (int i = 0; i < 16; ++i) {
    int e = e0 + i * 256;
    rows[i] = (e < nnz) ? r[e] : -1;
    if (rows[i] >= 0) atomicAdd(&lbase[rows[i] >> BIN_SHIFT], 1);
  }
  __syncthreads();

  // exclusive scan of per-bin counts
  int cv = lbase[t];
  int sc = cv;
#pragma unroll
  for (int d = 1; d < 64; d <<= 1) {
    int u = __shfl_up(sc, d);
    if (lane >= d) sc += u;
  }
  if (lane == 63) wsum[w] = sc;
  __syncthreads();
  int woff = 0;
  for (int i = 0; i < w; ++i) woff += wsum[i];
  int excl = woff + sc - cv;
  lbase[t] = excl;
  gofs[t] = cv ? atomicAdd(&bcur[t], cv) : 0;
  loff[t] = 0;
  __syncthreads();

  // place into LDS sorted by bin
#pragma unroll
  for (int i = 0; i < 16; ++i) {
    if (rows[i] >= 0) {
      int e = e0 + i * 256;
      int bin = rows[i] >> BIN_SHIFT;
      int o = atomicAdd(&loff[bin], 1);
      int pos = lbase[bin] + o;
      sbuf[pos] = make_int2(((rows[i] & (BIN_ROWS - 1)) << 18) | c[e],
                            __float_as_int(v[e]));
      binof[pos] = (unsigned char)bin;
    }
  }
  __syncthreads();

  // sorted write-out into slack-strided bin regions (overflow-guarded)
  for (int p = t; p < total; p += 256) {
    int bin = binof[p];
    int dst = gofs[bin] + (p - lbase[bin]);
    if (dst < bcap) tmp[(size_t)bin * bcap + dst] = sbuf[p];
  }
}

// ---------------------------------------------------------------- fill (per-bin counting sort)
// One block per (bin,list): sort the bin's tmp region by row in LDS, write ep
// sequentially into the same strided region; emit rs/re per row.
__global__ __launch_bounds__(256) void fill3_kernel(
    const int2* __restrict__ tmp1, const int2* __restrict__ tmp2,
    const int* __restrict__ bincur,
    int2* __restrict__ ep1, int2* __restrict__ ep2,
    int* __restrict__ rs1, int* __restrict__ re1,
    int* __restrict__ rs2, int* __restrict__ re2,
    int n, int bcap) {
  int L = blockIdx.y;
  int bin = blockIdx.x;
  const int2* tmp = (L ? tmp2 : tmp1) + (size_t)bin * bcap;
  int2* ep = L ? ep2 : ep1;
  int* rs = L ? rs2 : rs1;
  int* re = L ? re2 : re1;
  int count = bincur[L * MAX_BINS + bin];
  if (count > bcap) count = bcap;
  int bs = bin * bcap;  // dst base in ep

  __shared__ int cnt[BIN_ROWS];
  __shared__ int wsum[4];
  __shared__ int2 outbuf[FCAP];
  int t = threadIdx.x, lane = t & 63, w = t >> 6;
  cnt[2 * t] = 0;
  cnt[2 * t + 1] = 0;
  __syncthreads();

  for (int p = t; p < count; p += 256) {
    int rib = (unsigned)tmp[p].x >> 18;
    atomicAdd(&cnt[rib], 1);
  }
  __syncthreads();

  int a0 = cnt[2 * t], a1 = cnt[2 * t + 1];
  int pair = a0 + a1;
  int sc = pair;
#pragma unroll
  for (int d = 1; d < 64; d <<= 1) {
    int u = __shfl_up(sc, d);
    if (lane >= d) sc += u;
  }
  if (lane == 63) wsum[w] = sc;
  __syncthreads();
  int woff = 0;
  for (int i = 0; i < w; ++i) woff += wsum[i];
  int excl = woff + sc - pair;
  cnt[2 * t] = excl;
  cnt[2 * t + 1] = excl + a0;
  int row0 = (bin << BIN_SHIFT) + 2 * t;
  if (row0 < n) {
    rs[row0] = bs + excl;
    re[row0] = bs + excl + a0;
  }
  if (row0 + 1 < n) {
    rs[row0 + 1] = bs + excl + a0;
    re[row0 + 1] = bs + excl + a0 + a1;
  }
  __syncthreads();

  if (count <= FCAP) {
    for (int p = t; p < count; p += 256) {
      int2 ev = tmp[p];
      int rib = (unsigned)ev.x >> 18;
      int slot = atomicAdd(&cnt[rib], 1);
      outbuf[slot] = make_int2(ev.x & 0x3FFFF, ev.y);
    }
    __syncthreads();
    for (int p = t; p < count; p += 256) ep[bs + p] = outbuf[p];
  } else {
    for (int p = t; p < count; p += 256) {
      int2 ev = tmp[p];
      int rib = (unsigned)ev.x >> 18;
      int slot = atomicAdd(&cnt[rib], 1);
      ep[bs + slot] = make_int2(ev.x & 0x3FFFF, ev.y);
    }
  }
}

// ---------------------------------------------------------------- GEMM (both)
// H[row][col] = bf16( X[row][:] @ W[:][col] ), Wt bf16 [col][k], no LDS.
//   mfma_f32_16x16x32_bf16: A lane l: A[l&15][(l>>4)*8+e]; B: B[(l>>4)*8+e][l&15];
//   C/D: col=l&15, row=(l>>4)*4+reg.
__global__ __launch_bounds__(256) void gemm_both_kernel(
    const float* __restrict__ x1, const __hip_bfloat16* __restrict__ Wt1,
    __hip_bfloat16* __restrict__ h1, int n_r, int ng1,
    const float* __restrict__ x2, const __hip_bfloat16* __restrict__ Wt2,
    __hip_bfloat16* __restrict__ h2, int n_rp1) {
  int b = blockIdx.x;
  const float* X;
  const __hip_bfloat16* Wt;
  __hip_bfloat16* H;
  int n_rows, bb;
  if (b < ng1) { X = x1; Wt = Wt1; H = h1; n_rows = n_r; bb = b; }
  else         { X = x2; Wt = Wt2; H = h2; n_rows = n_rp1; bb = b - ng1; }

  int t = threadIdx.x;
  int lane = t & 63, wave = t >> 6;
  int rbase = bb * 128 + wave * 32;
  int lrow = lane & 15;
  int kq = (lane >> 4) * 8;

  int r0 = rbase + lrow;
  int r1r = r0 + 16;
  bool in0 = r0 < n_rows;
  bool in1 = r1r < n_rows;

  f32x4 acc0[8], acc1[8];
#pragma unroll
  for (int j = 0; j < 8; ++j) {
    acc0[j] = (f32x4){0.f, 0.f, 0.f, 0.f};
    acc1[j] = (f32x4){0.f, 0.f, 0.f, 0.f};
  }

  const float* x0p = X + (size_t)r0 * CDIM + kq;
  const float* x1p = X + (size_t)r1r * CDIM + kq;

  for (int kk = 0; kk < CDIM; kk += 32) {
    bf16x8 a0 = (bf16x8)(short)0, a1 = (bf16x8)(short)0;
    if (in0) {
      float4 u = *(const float4*)(x0p + kk);
      float4 vv = *(const float4*)(x0p + kk + 4);
      a0[0] = f2bf(u.x); a0[1] = f2bf(u.y); a0[2] = f2bf(u.z); a0[3] = f2bf(u.w);
      a0[4] = f2bf(vv.x); a0[5] = f2bf(vv.y); a0[6] = f2bf(vv.z); a0[7] = f2bf(vv.w);
    }
    if (in1) {
      float4 u = *(const float4*)(x1p + kk);
      float4 vv = *(const float4*)(x1p + kk + 4);
      a1[0] = f2bf(u.x); a1[1] = f2bf(u.y); a1[2] = f2bf(u.z); a1[3] = f2bf(u.w);
      a1[4] = f2bf(vv.x); a1[5] = f2bf(vv.y); a1[6] = f2bf(vv.z); a1[7] = f2bf(vv.w);
    }
    int k = kk + kq;
#pragma unroll
    for (int j = 0; j < 8; ++j) {
      int col = j * 16 + lrow;
      bf16x8 bv = *(const bf16x8*)(Wt + (size_t)col * CDIM + k);
      acc0[j] = __builtin_amdgcn_mfma_f32_16x16x32_bf16(a0, bv, acc0[j], 0, 0, 0);
      acc1[j] = __builtin_amdgcn_mfma_f32_16x16x32_bf16(a1, bv, acc1[j], 0, 0, 0);
    }
  }

  int crow = rbase + (lane >> 4) * 4;
#pragma unroll
  for (int j = 0; j < 8; ++j) {
    int col = j * 16 + lrow;
#pragma unroll
    for (int rr = 0; rr < 4; ++rr) {
      int row0 = crow + rr;
      if (row0 < n_rows) {
        union { __hip_bfloat16 h; short s; } u;
        u.s = f2bf(acc0[j][rr]);
        H[(size_t)row0 * CDIM + col] = u.h;
      }
      int row1 = crow + 16 + rr;
      if (row1 < n_rows) {
        union { __hip_bfloat16 h; short s; } u;
        u.s = f2bf(acc1[j][rr]);
        H[(size_t)row1 * CDIM + col] = u.h;
      }
    }
  }
}

// ---------------------------------------------------------------- fused SpMM + ELU + add
// 16-lane group per row (16 rows per 256-block); lane owns 8 channels via one
// dwordx4 gather per edge; h row = CDIM*2B = 16 uint4 -> index = col*16 + l.
__global__ __launch_bounds__(256) void spmm_out_kernel(
    const int* __restrict__ rs1, const int* __restrict__ re1,
    const int2* __restrict__ ep1, const uint4* __restrict__ h1,
    const int* __restrict__ rs2, const int* __restrict__ re2,
    const int2* __restrict__ ep2, const uint4* __restrict__ h2,
    float* __restrict__ out, int n_r) {
  int t = threadIdx.x;
  int g = t >> 4;
  int l = t & 15;
  int row = blockIdx.x * 16 + g;
  if (row >= n_r) return;

  f32x2 res[4];
#pragma unroll
  for (int j = 0; j < 4; ++j) res[j] = f32x2{0.f, 0.f};

#pragma unroll
  for (int L = 0; L < 2; ++L) {
    const int* rs = L ? rs2 : rs1;
    const int* re = L ? re2 : re1;
    const int2* ep = L ? ep2 : ep1;
    const uint4* h = L ? h2 : h1;
    int s = rs[row], e = re[row];

    f32x2 a[4], b[4];
#pragma unroll
    for (int j = 0; j < 4; ++j) { a[j] = f32x2{0.f, 0.f}; b[j] = f32x2{0.f, 0.f}; }

    int i = s;
    for (; i + 1 < e; i += 2) {
      int2 e0 = ep[i];
      int2 e1 = ep[i + 1];
      uint4 p0 = h[(unsigned)e0.x * (CDIM / 8) + l];   // row stride = 16 uint4
      uint4 p1 = h[(unsigned)e1.x * (CDIM / 8) + l];
      float va = __int_as_float(e0.y);
      float vb = __int_as_float(e1.y);
      f32x2 v0 = f32x2{va, va};
      f32x2 v1 = f32x2{vb, vb};
      a[0] += v0 * up2(p0.x);
      a[1] += v0 * up2(p0.y);
      a[2] += v0 * up2(p0.z);
      a[3] += v0 * up2(p0.w);
      b[0] += v1 * up2(p1.x);
      b[1] += v1 * up2(p1.y);
      b[2] += v1 * up2(p1.z);
      b[3] += v1 * up2(p1.w);
    }
    if (i < e) {
      int2 e0 = ep[i];
      uint4 p0 = h[(unsigned)e0.x * (CDIM / 8) + l];
      float va = __int_as_float(e0.y);
      f32x2 v0 = f32x2{va, va};
      a[0] += v0 * up2(p0.x);
      a[1] += v0 * up2(p0.y);
      a[2] += v0 * up2(p0.z);
      a[3] += v0 * up2(p0.w);
    }
#pragma unroll
    for (int j = 0; j < 4; ++j) {
      f32x2 sv = a[j] + b[j];
      sv.x = elu1(sv.x);
      sv.y = elu1(sv.y);
      res[j] += sv;
    }
  }

  float* dst = out + (size_t)row * CDIM + l * 8;
  *(float4*)dst = make_float4(res[0].x, res[0].y, res[1].x, res[1].y);
  *(float4*)(dst + 4) = make_float4(res[2].x, res[2].y, res[3].x, res[3].y);
}

// ---------------------------------------------------------------- launch
extern "C" void kernel_launch(void* const* d_in, const int* in_sizes, int n_in,
                              void* d_out, int out_size, void* d_ws, size_t ws_size,
                              hipStream_t stream) {
  const float* x1  = (const float*)d_in[0];
  const float* x2  = (const float*)d_in[1];
  const float* W1  = (const float*)d_in[2];
  const float* W2  = (const float*)d_in[3];
  const float* v11 = (const float*)d_in[4];
  const float* v21 = (const float*)d_in[5];
  const int* r11   = (const int*)d_in[6];
  const int* c11   = (const int*)d_in[7];
  const int* r21   = (const int*)d_in[8];
  const int* c21   = (const int*)d_in[9];

  int n_r   = in_sizes[0] / CDIM;
  int n_rp1 = in_sizes[1] / CDIM;
  int nnz   = in_sizes[4];
  float* out = (float*)d_out;
  int nbins = (n_r + BIN_ROWS - 1) >> BIN_SHIFT;  // 196; must be <= MAX_BINS
  int bcap = ((nnz / nbins) * 9 / 8 + 511) & ~511;  // 9216 (mean 8192/bin, +11 sigma)

  char* ws = (char*)d_ws;
  size_t off = 0;
  auto alloc = [&](size_t bytes) -> void* {
    void* p = ws + off;
    off = (off + bytes + 255) & ~(size_t)255;
    return p;
  };
  size_t binned = (size_t)nbins * bcap * 8;  // 14.5 MB each
  __hip_bfloat16* h1 = (__hip_bfloat16*)alloc((size_t)n_r * CDIM * 2);    // 25.6 MB
  __hip_bfloat16* h2 = (__hip_bfloat16*)alloc((size_t)n_rp1 * CDIM * 2);  // 51.2 MB
  __hip_bfloat16* Wt1 = (__hip_bfloat16*)alloc(CDIM * CDIM * 2);
  __hip_bfloat16* Wt2 = (__hip_bfloat16*)alloc(CDIM * CDIM * 2);
  int* rs1 = (int*)alloc((size_t)n_r * 4);
  int* re1 = (int*)alloc((size_t)n_r * 4);
  int* rs2 = (int*)alloc((size_t)n_r * 4);
  int* re2 = (int*)alloc((size_t)n_r * 4);
  int* bincur = (int*)alloc(2 * MAX_BINS * 4);
  int2* ep1 = (int2*)alloc(binned);
  int2* ep2 = (int2*)alloc(binned);
  int2* tmp1 = (int2*)alloc(binned);
  int2* tmp2 = (int2*)alloc(binned);
  (void)ws_size;  // ~137 MB of workspace

  hipMemsetAsync(bincur, 0, 2 * MAX_BINS * 4, stream);

  int npart = (nnz + PCHUNK - 1) / PCHUNK;  // 391
  int ng1 = (n_r + 127) / 128;              // 782
  int ng2 = (n_rp1 + 127) / 128;            // 1563

  part_prep_kernel<<<2 * npart + 2, 256, 0, stream>>>(
      r11, c11, v11, r21, c21, v21, bincur, tmp1, tmp2, nnz, npart, bcap,
      W1, W2, Wt1, Wt2);

  fill3_kernel<<<dim3(nbins, 2), 256, 0, stream>>>(
      tmp1, tmp2, bincur, ep1, ep2, rs1, re1, rs2, re2, n_r, bcap);

  gemm_both_kernel<<<ng1 + ng2, 256, 0, stream>>>(
      x1, Wt1, h1, n_r, ng1, x2, Wt2, h2, n_rp1);

  spmm_out_kernel<<<(n_r + 15) / 16, 256, 0, stream>>>(
      rs1, re1, ep1, (const uint4*)h1,
      rs2, re2, ep2, (const uint4*)h2, out, n_r);
}

// Round 9
// 271.763 us; speedup vs baseline: 2.5192x; 1.0245x over previous
//
#include <hip/hip_runtime.h>
#include <hip/hip_bf16.h>

// Sizes (runtime): N_R = 100000, N_RP1 = 200000, NNZ = 1600000, C = 128
//
// Pipeline (5 dispatches):
//   1. memset bincur (bin cursors) to 0
//   2. part_prep: bin edges by row>>9 into slack-strided tmp regions
//      (bin b owns [b*bcap, (b+1)*bcap)); per-block LDS counting sort by bin
//      so tmp writes are sorted runs. +2 blocks convert W -> bf16 W^T.
//   3. fill3: one block per (bin,list): LDS counting sort by row ->
//      sequential ep writes into the bin's region; emits rs[]/re[] per row.
//   4. gemm_both: h = bf16(X @ W) via mfma_f32_16x16x32_bf16 (LDS-free).
//      Runs RIGHT BEFORE spmm so h (77 MB) stays hot in the 256MB L3.
//   5. spmm_out: 16-lane group per row; lane = 8 channels via one dwordx4
//      gather (h row = 16 uint4); unroll x4 = 4 independent gather chains
//      in flight (latency hiding); 2 accumulator sets; __expf ELU.

#define CDIM 128
#define BIN_SHIFT 9            // 512 rows per bin
#define BIN_ROWS (1 << BIN_SHIFT)
#define MAX_BINS 256           // supports n_r <= 131072
#define PCHUNK 4096            // edges per partition block
#define FCAP 9216              // fill3 LDS staging capacity (72KB)

typedef __attribute__((ext_vector_type(8))) short bf16x8;
typedef __attribute__((ext_vector_type(4))) float f32x4;
typedef __attribute__((ext_vector_type(2))) float f32x2;

static __device__ __forceinline__ short f2bf(float f) {
  __hip_bfloat16 h = __float2bfloat16(f);
  union { __hip_bfloat16 h; short s; } u;
  u.h = h;
  return u.s;
}

static __device__ __forceinline__ f32x2 up2(unsigned u) {
  return f32x2{__uint_as_float(u << 16), __uint_as_float(u & 0xffff0000u)};
}

static __device__ __forceinline__ float elu1(float x) {
  return x > 0.f ? x : __expf(x) - 1.f;
}

// ---------------------------------------------------------------- partition + prep_w
// Slack bins: bin b region = [b*bcap, b*bcap + bincur[b]); cursors zero-init.
// Packed entry: x = (row_in_bin << 18) | col, y = val bits.
__global__ __launch_bounds__(256) void part_prep_kernel(
    const int* __restrict__ r1, const int* __restrict__ c1, const float* __restrict__ v1,
    const int* __restrict__ r2, const int* __restrict__ c2, const float* __restrict__ v2,
    int* __restrict__ bincur, int2* __restrict__ tmp1, int2* __restrict__ tmp2,
    int nnz, int npart, int bcap,
    const float* __restrict__ W1, const float* __restrict__ W2,
    __hip_bfloat16* __restrict__ Wt1, __hip_bfloat16* __restrict__ Wt2) {
  int b = blockIdx.x;
  int t = threadIdx.x;
  if (b >= 2 * npart) {
    // ---- prep_w (2 blocks) ----
    int wb = b - 2 * npart;
    const float* W = wb ? W2 : W1;
    __hip_bfloat16* Wt = wb ? Wt2 : Wt1;
    for (int idx = t; idx < CDIM * CDIM; idx += 256) {
      int k = idx >> 7, n = idx & 127;
      union { __hip_bfloat16 h; short s; } u;
      u.s = f2bf(W[idx]);
      Wt[n * CDIM + k] = u.h;
    }
    return;
  }

  __shared__ int lbase[MAX_BINS];   // counts, then local exclusive scan
  __shared__ int gofs[MAX_BINS];    // global within-bin offset for this block
  __shared__ int loff[MAX_BINS];
  __shared__ int wsum[4];
  __shared__ int2 sbuf[PCHUNK];
  __shared__ unsigned char binof[PCHUNK];

  int list = b >= npart;
  int pb = list ? b - npart : b;
  const int* r = list ? r2 : r1;
  const int* c = list ? c2 : c1;
  const float* v = list ? v2 : v1;
  int2* tmp = list ? tmp2 : tmp1;
  int* bcur = bincur + list * MAX_BINS;

  int lane = t & 63, w = t >> 6;
  lbase[t] = 0;
  __syncthreads();

  int e0 = pb * PCHUNK + t;
  int total = nnz - pb * PCHUNK;
  if (total > PCHUNK) total = PCHUNK;

  int rows[16];
#pragma unroll
  for (int i = 0; i < 16; ++i) {
    int e = e0 + i * 256;
    rows[i] = (e < nnz) ? r[e] : -1;
    if (rows[i] >= 0) atomicAdd(&lbase[rows[i] >> BIN_SHIFT], 1);
  }
  __syncthreads();

  // exclusive scan of per-bin counts
  int cv = lbase[t];
  int sc = cv;
#pragma unroll
  for (int d = 1; d < 64; d <<= 1) {
    int u = __shfl_up(sc, d);
    if (lane >= d) sc += u;
  }
  if (lane == 63) wsum[w] = sc;
  __syncthreads();
  int woff = 0;
  for (int i = 0; i < w; ++i) woff += wsum[i];
  int excl = woff + sc - cv;
  lbase[t] = excl;
  gofs[t] = cv ? atomicAdd(&bcur[t], cv) : 0;
  loff[t] = 0;
  __syncthreads();

  // place into LDS sorted by bin
#pragma unroll
  for (int i = 0; i < 16; ++i) {
    if (rows[i] >= 0) {
      int e = e0 + i * 256;
      int bin = rows[i] >> BIN_SHIFT;
      int o = atomicAdd(&loff[bin], 1);
      int pos = lbase[bin] + o;
      sbuf[pos] = make_int2(((rows[i] & (BIN_ROWS - 1)) << 18) | c[e],
                            __float_as_int(v[e]));
      binof[pos] = (unsigned char)bin;
    }
  }
  __syncthreads();

  // sorted write-out into slack-strided bin regions (overflow-guarded)
  for (int p = t; p < total; p += 256) {
    int bin = binof[p];
    int dst = gofs[bin] + (p - lbase[bin]);
    if (dst < bcap) tmp[(size_t)bin * bcap + dst] = sbuf[p];
  }
}

// ---------------------------------------------------------------- fill (per-bin counting sort)
// One block per (bin,list): sort the bin's tmp region by row in LDS, write ep
// sequentially into the same strided region; emit rs/re per row.
__global__ __launch_bounds__(256) void fill3_kernel(
    const int2* __restrict__ tmp1, const int2* __restrict__ tmp2,
    const int* __restrict__ bincur,
    int2* __restrict__ ep1, int2* __restrict__ ep2,
    int* __restrict__ rs1, int* __restrict__ re1,
    int* __restrict__ rs2, int* __restrict__ re2,
    int n, int bcap) {
  int L = blockIdx.y;
  int bin = blockIdx.x;
  const int2* tmp = (L ? tmp2 : tmp1) + (size_t)bin * bcap;
  int2* ep = L ? ep2 : ep1;
  int* rs = L ? rs2 : rs1;
  int* re = L ? re2 : re1;
  int count = bincur[L * MAX_BINS + bin];
  if (count > bcap) count = bcap;
  int bs = bin * bcap;  // dst base in ep

  __shared__ int cnt[BIN_ROWS];
  __shared__ int wsum[4];
  __shared__ int2 outbuf[FCAP];
  int t = threadIdx.x, lane = t & 63, w = t >> 6;
  cnt[2 * t] = 0;
  cnt[2 * t + 1] = 0;
  __syncthreads();

  for (int p = t; p < count; p += 256) {
    int rib = (unsigned)tmp[p].x >> 18;
    atomicAdd(&cnt[rib], 1);
  }
  __syncthreads();

  int a0 = cnt[2 * t], a1 = cnt[2 * t + 1];
  int pair = a0 + a1;
  int sc = pair;
#pragma unroll
  for (int d = 1; d < 64; d <<= 1) {
    int u = __shfl_up(sc, d);
    if (lane >= d) sc += u;
  }
  if (lane == 63) wsum[w] = sc;
  __syncthreads();
  int woff = 0;
  for (int i = 0; i < w; ++i) woff += wsum[i];
  int excl = woff + sc - pair;
  cnt[2 * t] = excl;
  cnt[2 * t + 1] = excl + a0;
  int row0 = (bin << BIN_SHIFT) + 2 * t;
  if (row0 < n) {
    rs[row0] = bs + excl;
    re[row0] = bs + excl + a0;
  }
  if (row0 + 1 < n) {
    rs[row0 + 1] = bs + excl + a0;
    re[row0 + 1] = bs + excl + a0 + a1;
  }
  __syncthreads();

  if (count <= FCAP) {
    for (int p = t; p < count; p += 256) {
      int2 ev = tmp[p];
      int rib = (unsigned)ev.x >> 18;
      int slot = atomicAdd(&cnt[rib], 1);
      outbuf[slot] = make_int2(ev.x & 0x3FFFF, ev.y);
    }
    __syncthreads();
    for (int p = t; p < count; p += 256) ep[bs + p] = outbuf[p];
  } else {
    for (int p = t; p < count; p += 256) {
      int2 ev = tmp[p];
      int rib = (unsigned)ev.x >> 18;
      int slot = atomicAdd(&cnt[rib], 1);
      ep[bs + slot] = make_int2(ev.x & 0x3FFFF, ev.y);
    }
  }
}

// ---------------------------------------------------------------- GEMM (both)
// H[row][col] = bf16( X[row][:] @ W[:][col] ), Wt bf16 [col][k], no LDS.
//   mfma_f32_16x16x32_bf16: A lane l: A[l&15][(l>>4)*8+e]; B: B[(l>>4)*8+e][l&15];
//   C/D: col=l&15, row=(l>>4)*4+reg.
__global__ __launch_bounds__(256) void gemm_both_kernel(
    const float* __restrict__ x1, const __hip_bfloat16* __restrict__ Wt1,
    __hip_bfloat16* __restrict__ h1, int n_r, int ng1,
    const float* __restrict__ x2, const __hip_bfloat16* __restrict__ Wt2,
    __hip_bfloat16* __restrict__ h2, int n_rp1) {
  int b = blockIdx.x;
  const float* X;
  const __hip_bfloat16* Wt;
  __hip_bfloat16* H;
  int n_rows, bb;
  if (b < ng1) { X = x1; Wt = Wt1; H = h1; n_rows = n_r; bb = b; }
  else         { X = x2; Wt = Wt2; H = h2; n_rows = n_rp1; bb = b - ng1; }

  int t = threadIdx.x;
  int lane = t & 63, wave = t >> 6;
  int rbase = bb * 128 + wave * 32;
  int lrow = lane & 15;
  int kq = (lane >> 4) * 8;

  int r0 = rbase + lrow;
  int r1r = r0 + 16;
  bool in0 = r0 < n_rows;
  bool in1 = r1r < n_rows;

  f32x4 acc0[8], acc1[8];
#pragma unroll
  for (int j = 0; j < 8; ++j) {
    acc0[j] = (f32x4){0.f, 0.f, 0.f, 0.f};
    acc1[j] = (f32x4){0.f, 0.f, 0.f, 0.f};
  }

  const float* x0p = X + (size_t)r0 * CDIM + kq;
  const float* x1p = X + (size_t)r1r * CDIM + kq;

  for (int kk = 0; kk < CDIM; kk += 32) {
    bf16x8 a0 = (bf16x8)(short)0, a1 = (bf16x8)(short)0;
    if (in0) {
      float4 u = *(const float4*)(x0p + kk);
      float4 vv = *(const float4*)(x0p + kk + 4);
      a0[0] = f2bf(u.x); a0[1] = f2bf(u.y); a0[2] = f2bf(u.z); a0[3] = f2bf(u.w);
      a0[4] = f2bf(vv.x); a0[5] = f2bf(vv.y); a0[6] = f2bf(vv.z); a0[7] = f2bf(vv.w);
    }
    if (in1) {
      float4 u = *(const float4*)(x1p + kk);
      float4 vv = *(const float4*)(x1p + kk + 4);
      a1[0] = f2bf(u.x); a1[1] = f2bf(u.y); a1[2] = f2bf(u.z); a1[3] = f2bf(u.w);
      a1[4] = f2bf(vv.x); a1[5] = f2bf(vv.y); a1[6] = f2bf(vv.z); a1[7] = f2bf(vv.w);
    }
    int k = kk + kq;
#pragma unroll
    for (int j = 0; j < 8; ++j) {
      int col = j * 16 + lrow;
      bf16x8 bv = *(const bf16x8*)(Wt + (size_t)col * CDIM + k);
      acc0[j] = __builtin_amdgcn_mfma_f32_16x16x32_bf16(a0, bv, acc0[j], 0, 0, 0);
      acc1[j] = __builtin_amdgcn_mfma_f32_16x16x32_bf16(a1, bv, acc1[j], 0, 0, 0);
    }
  }

  int crow = rbase + (lane >> 4) * 4;
#pragma unroll
  for (int j = 0; j < 8; ++j) {
    int col = j * 16 + lrow;
#pragma unroll
    for (int rr = 0; rr < 4; ++rr) {
      int row0 = crow + rr;
      if (row0 < n_rows) {
        union { __hip_bfloat16 h; short s; } u;
        u.s = f2bf(acc0[j][rr]);
        H[(size_t)row0 * CDIM + col] = u.h;
      }
      int row1 = crow + 16 + rr;
      if (row1 < n_rows) {
        union { __hip_bfloat16 h; short s; } u;
        u.s = f2bf(acc1[j][rr]);
        H[(size_t)row1 * CDIM + col] = u.h;
      }
    }
  }
}

// ---------------------------------------------------------------- fused SpMM + ELU + add
// 16-lane group per row; lane owns 8 channels via one dwordx4 gather per edge
// (h row = 16 uint4). Unroll x4: 4 independent gathers in flight per thread,
// 2 accumulator sets (loads need independence; FMA dep is only ~4 cyc).
__global__ __launch_bounds__(256) void spmm_out_kernel(
    const int* __restrict__ rs1, const int* __restrict__ re1,
    const int2* __restrict__ ep1, const uint4* __restrict__ h1,
    const int* __restrict__ rs2, const int* __restrict__ re2,
    const int2* __restrict__ ep2, const uint4* __restrict__ h2,
    float* __restrict__ out, int n_r) {
  int t = threadIdx.x;
  int g = t >> 4;
  int l = t & 15;
  int row = blockIdx.x * 16 + g;
  if (row >= n_r) return;

  f32x2 res[4];
#pragma unroll
  for (int j = 0; j < 4; ++j) res[j] = f32x2{0.f, 0.f};

#pragma unroll
  for (int L = 0; L < 2; ++L) {
    const int* rs = L ? rs2 : rs1;
    const int* re = L ? re2 : re1;
    const int2* ep = L ? ep2 : ep1;
    const uint4* h = L ? h2 : h1;
    int s = rs[row], e = re[row];

    f32x2 a[4], b[4];
#pragma unroll
    for (int j = 0; j < 4; ++j) { a[j] = f32x2{0.f, 0.f}; b[j] = f32x2{0.f, 0.f}; }

    int i = s;
    for (; i + 3 < e; i += 4) {
      int2 e0 = ep[i];
      int2 e1 = ep[i + 1];
      int2 e2 = ep[i + 2];
      int2 e3 = ep[i + 3];
      uint4 p0 = h[(unsigned)e0.x * (CDIM / 8) + l];
      uint4 p1 = h[(unsigned)e1.x * (CDIM / 8) + l];
      uint4 p2 = h[(unsigned)e2.x * (CDIM / 8) + l];
      uint4 p3 = h[(unsigned)e3.x * (CDIM / 8) + l];
      f32x2 v0 = f32x2{__int_as_float(e0.y), __int_as_float(e0.y)};
      f32x2 v1 = f32x2{__int_as_float(e1.y), __int_as_float(e1.y)};
      f32x2 v2 = f32x2{__int_as_float(e2.y), __int_as_float(e2.y)};
      f32x2 v3 = f32x2{__int_as_float(e3.y), __int_as_float(e3.y)};
      a[0] += v0 * up2(p0.x); a[1] += v0 * up2(p0.y);
      a[2] += v0 * up2(p0.z); a[3] += v0 * up2(p0.w);
      b[0] += v1 * up2(p1.x); b[1] += v1 * up2(p1.y);
      b[2] += v1 * up2(p1.z); b[3] += v1 * up2(p1.w);
      a[0] += v2 * up2(p2.x); a[1] += v2 * up2(p2.y);
      a[2] += v2 * up2(p2.z); a[3] += v2 * up2(p2.w);
      b[0] += v3 * up2(p3.x); b[1] += v3 * up2(p3.y);
      b[2] += v3 * up2(p3.z); b[3] += v3 * up2(p3.w);
    }
    for (; i < e; ++i) {
      int2 e0 = ep[i];
      uint4 p0 = h[(unsigned)e0.x * (CDIM / 8) + l];
      f32x2 v0 = f32x2{__int_as_float(e0.y), __int_as_float(e0.y)};
      a[0] += v0 * up2(p0.x); a[1] += v0 * up2(p0.y);
      a[2] += v0 * up2(p0.z); a[3] += v0 * up2(p0.w);
    }
#pragma unroll
    for (int j = 0; j < 4; ++j) {
      f32x2 sv = a[j] + b[j];
      sv.x = elu1(sv.x);
      sv.y = elu1(sv.y);
      res[j] += sv;
    }
  }

  float* dst = out + (size_t)row * CDIM + l * 8;
  *(float4*)dst = make_float4(res[0].x, res[0].y, res[1].x, res[1].y);
  *(float4*)(dst + 4) = make_float4(res[2].x, res[2].y, res[3].x, res[3].y);
}

// ---------------------------------------------------------------- launch
extern "C" void kernel_launch(void* const* d_in, const int* in_sizes, int n_in,
                              void* d_out, int out_size, void* d_ws, size_t ws_size,
                              hipStream_t stream) {
  const float* x1  = (const float*)d_in[0];
  const float* x2  = (const float*)d_in[1];
  const float* W1  = (const float*)d_in[2];
  const float* W2  = (const float*)d_in[3];
  const float* v11 = (const float*)d_in[4];
  const float* v21 = (const float*)d_in[5];
  const int* r11   = (const int*)d_in[6];
  const int* c11   = (const int*)d_in[7];
  const int* r21   = (const int*)d_in[8];
  const int* c21   = (const int*)d_in[9];

  int n_r   = in_sizes[0] / CDIM;
  int n_rp1 = in_sizes[1] / CDIM;
  int nnz   = in_sizes[4];
  float* out = (float*)d_out;
  int nbins = (n_r + BIN_ROWS - 1) >> BIN_SHIFT;  // 196; must be <= MAX_BINS
  int bcap = ((nnz / nbins) * 9 / 8 + 511) & ~511;  // 9216 (mean 8192/bin, +11 sigma)

  char* ws = (char*)d_ws;
  size_t off = 0;
  auto alloc = [&](size_t bytes) -> void* {
    void* p = ws + off;
    off = (off + bytes + 255) & ~(size_t)255;
    return p;
  };
  size_t binned = (size_t)nbins * bcap * 8;  // 14.5 MB each
  __hip_bfloat16* h1 = (__hip_bfloat16*)alloc((size_t)n_r * CDIM * 2);    // 25.6 MB
  __hip_bfloat16* h2 = (__hip_bfloat16*)alloc((size_t)n_rp1 * CDIM * 2);  // 51.2 MB
  __hip_bfloat16* Wt1 = (__hip_bfloat16*)alloc(CDIM * CDIM * 2);
  __hip_bfloat16* Wt2 = (__hip_bfloat16*)alloc(CDIM * CDIM * 2);
  int* rs1 = (int*)alloc((size_t)n_r * 4);
  int* re1 = (int*)alloc((size_t)n_r * 4);
  int* rs2 = (int*)alloc((size_t)n_r * 4);
  int* re2 = (int*)alloc((size_t)n_r * 4);
  int* bincur = (int*)alloc(2 * MAX_BINS * 4);
  int2* ep1 = (int2*)alloc(binned);
  int2* ep2 = (int2*)alloc(binned);
  int2* tmp1 = (int2*)alloc(binned);
  int2* tmp2 = (int2*)alloc(binned);
  (void)ws_size;  // ~137 MB of workspace

  hipMemsetAsync(bincur, 0, 2 * MAX_BINS * 4, stream);

  int npart = (nnz + PCHUNK - 1) / PCHUNK;  // 391
  int ng1 = (n_r + 127) / 128;              // 782
  int ng2 = (n_rp1 + 127) / 128;            // 1563

  part_prep_kernel<<<2 * npart + 2, 256, 0, stream>>>(
      r11, c11, v11, r21, c21, v21, bincur, tmp1, tmp2, nnz, npart, bcap,
      W1, W2, Wt1, Wt2);

  fill3_kernel<<<dim3(nbins, 2), 256, 0, stream>>>(
      tmp1, tmp2, bincur, ep1, ep2, rs1, re1, rs2, re2, n_r, bcap);

  gemm_both_kernel<<<ng1 + ng2, 256, 0, stream>>>(
      x1, Wt1, h1, n_r, ng1, x2, Wt2, h2, n_rp1);

  spmm_out_kernel<<<(n_r + 15) / 16, 256, 0, stream>>>(
      rs1, re1, ep1, (const uint4*)h1,
      rs2, re2, ep2, (const uint4*)h2, out, n_r);
}